// Round 9
// baseline (2507.708 us; speedup 1.0000x reference)
//
#include <hip/hip_runtime.h>
#include <math.h>

#define B 256
#define L 256
#define H 512
#define H3 1536
#define TOKV 128
#define EOS_TOK 1
#define OUTC 257
#define SLOT ((size_t)B * H)   // elements per h-state

typedef short s16;
typedef s16 s16x8 __attribute__((ext_vector_type(8)));
typedef s16 s16x4 __attribute__((ext_vector_type(4)));
typedef float f32x4v __attribute__((ext_vector_type(4)));
typedef unsigned long long u64;

__device__ __forceinline__ float sigmoidf_(float x) {
    return 1.0f / (1.0f + __expf(-x));
}

// fp32 -> bf16 bit pattern, round-to-nearest-even (same as (__bf16) cast)
__device__ __forceinline__ s16 f2bf(float x) {
    unsigned u = __builtin_bit_cast(unsigned, x);
    u += 0x7fffu + ((u >> 16) & 1u);
    return (s16)(u >> 16);
}
__device__ __forceinline__ float bf2f(s16 h) {
    return __builtin_bit_cast(float, ((unsigned)(unsigned short)h) << 16);
}
// pack hi(low16)|lo(high16) of a float's 2-term bf16 split
__device__ __forceinline__ unsigned packsplit(float x) {
    s16 hh = f2bf(x);
    s16 ll = f2bf(x - bf2f(hh));
    return (unsigned)(unsigned short)hh | ((unsigned)(unsigned short)ll << 16);
}

// device-scope (sc1) 8B load with immediate offset, volatile-ordered.
template<int BOFF>
__device__ __forceinline__ u64 gld_sc1(const u64* base) {
    u64 d;
    asm volatile("global_load_dwordx2 %0, %1, off offset:%2 sc1"
                 : "=v"(d) : "v"(base), "n"(BOFF));
    return d;
}
// batch-issue 64 loads (16 k-chunks x 4), offsets kc*128 + ii*8 bytes
template<int KC>
struct LoadAll {
    static __device__ __forceinline__ void run(const u64* base, u64* dst) {
        dst[KC * 4 + 0] = gld_sc1<KC * 128 + 0>(base);
        dst[KC * 4 + 1] = gld_sc1<KC * 128 + 8>(base);
        dst[KC * 4 + 2] = gld_sc1<KC * 128 + 16>(base);
        dst[KC * 4 + 3] = gld_sc1<KC * 128 + 24>(base);
        LoadAll<KC + 1>::run(base, dst);
    }
};
template<>
struct LoadAll<16> {
    static __device__ __forceinline__ void run(const u64*, u64*) {}
};

// ---------------- per-cluster barrier (monotonic, relaxed + compiler fences) ----------------
// Data flows via sc1 ops (hardware-coherent at the device coherence point).
// HW ordering: __syncthreads drains vmcnt (stores complete at coherence point)
// before tid0's add; counter & data share the coherence point, so observing the
// count implies data visibility for subsequent sc1 loads. The asm fences pin
// the COMPILER ordering (no atomic/load motion across the spin).
__device__ __forceinline__ void clusterbar(unsigned* bar, int c, unsigned n, int tid) {
    __syncthreads();
    if (tid == 0) {
        const unsigned tgt = 32u * n;
        unsigned* ctr = bar + c * 32;
        asm volatile("" ::: "memory");
        __hip_atomic_fetch_add(ctr, 1u, __ATOMIC_RELAXED, __HIP_MEMORY_SCOPE_AGENT);
        while (__hip_atomic_load(ctr, __ATOMIC_RELAXED, __HIP_MEMORY_SCOPE_AGENT) < tgt)
            __builtin_amdgcn_s_sleep(1);
        asm volatile("" ::: "memory");
    }
    __syncthreads();
}

// ---------------- prep: elementwise split of a fp32 weight array ----------------
__global__ __launch_bounds__(256) void k_split(const float* __restrict__ src,
                                               s16* __restrict__ hi,
                                               s16* __restrict__ lo, int n4) {
    int i = blockIdx.x * 256 + threadIdx.x;
    if (i >= n4) return;
    float4 x = ((const float4*)src)[i];
    float xs[4] = {x.x, x.y, x.z, x.w};
    s16x4 h, l;
    #pragma unroll
    for (int q = 0; q < 4; ++q) {
        s16 hh = f2bf(xs[q]);
        h[q] = hh;
        l[q] = f2bf(xs[q] - bf2f(hh));
    }
    *(s16x4*)(hi + (size_t)i * 4) = h;
    *(s16x4*)(lo + (size_t)i * 4) = l;
}

// ---------------- prep: gi_tok[v][j] = relu(token_emb[v]) . w_ih[j] + b_ih[j] (fp32) ----------------
__global__ __launch_bounds__(256) void k_gi_tok(
        const float* __restrict__ token_emb, const float* __restrict__ w_ih,
        const float* __restrict__ b_ih, float* __restrict__ gi_out) {
    __shared__ float wlds[96][132];
    __shared__ float elds[16][132];
    const int vi = blockIdx.x >> 4;
    const int ji = blockIdx.x & 15;
    const int v0 = vi << 4, j0 = ji * 96;
    const int tid = threadIdx.x;
    const int vl = tid & 7;
    const int jl = tid >> 3;
    float acc[2][3] = {{0.f, 0.f, 0.f}, {0.f, 0.f, 0.f}};
    for (int ck = 0; ck < 4; ++ck) {
        const int c0 = ck << 7;
        __syncthreads();
        for (int i = tid; i < 96 * 32; i += 256) {
            int row = i >> 5, c4 = i & 31;
            *(float4*)&wlds[row][c4 << 2] =
                *(const float4*)(w_ih + (size_t)(j0 + row) * H + c0 + (c4 << 2));
        }
        for (int i = tid; i < 16 * 32; i += 256) {
            int row = i >> 5, c4 = i & 31;
            float4 e = *(const float4*)(token_emb + (size_t)(v0 + row) * H + c0 + (c4 << 2));
            e.x = fmaxf(e.x, 0.f); e.y = fmaxf(e.y, 0.f);
            e.z = fmaxf(e.z, 0.f); e.w = fmaxf(e.w, 0.f);
            *(float4*)&elds[row][c4 << 2] = e;
        }
        __syncthreads();
        #pragma unroll 8
        for (int c = 0; c < 128; c += 4) {
            float4 wa = *(const float4*)&wlds[jl][c];
            float4 wb = *(const float4*)&wlds[32 + jl][c];
            float4 wc = *(const float4*)&wlds[64 + jl][c];
            float4 ea = *(const float4*)&elds[vl][c];
            float4 eb = *(const float4*)&elds[vl + 8][c];
            acc[0][0] += ea.x*wa.x + ea.y*wa.y + ea.z*wa.z + ea.w*wa.w;
            acc[0][1] += ea.x*wb.x + ea.y*wb.y + ea.z*wb.z + ea.w*wb.w;
            acc[0][2] += ea.x*wc.x + ea.y*wc.y + ea.z*wc.z + ea.w*wc.w;
            acc[1][0] += eb.x*wa.x + eb.y*wa.y + eb.z*wa.z + eb.w*wa.w;
            acc[1][1] += eb.x*wb.x + eb.y*wb.y + eb.z*wb.z + eb.w*wb.w;
            acc[1][2] += eb.x*wc.x + eb.y*wc.y + eb.z*wc.z + eb.w*wc.w;
        }
    }
    #pragma unroll
    for (int p = 0; p < 2; ++p) {
        int v = v0 + vl + (p << 3);
        #pragma unroll
        for (int s = 0; s < 3; ++s) {
            int j = j0 + (s << 5) + jl;
            gi_out[(size_t)v * H3 + j] = acc[p][s] + b_ih[j];
        }
    }
}

// ---------------- persistent GRU scan, clustered (cooperative, 256 WGs x 128 thr) ----------------
// WG wg: cluster c = wg&7 (rows c*32..+32), j-slice jt = wg>>3 (cols jt*16..+16).
// Weights in LDS fragment-major (conflict-free). h exchange via packed u32
// (bf16 hi|lo<<16) sc1 ops. A-loads are 64 volatile-asm sc1 loads issued
// back-to-back (forced single IF latency), then waitcnt + sched_barrier(0).
__global__ __launch_bounds__(128, 1) void k_scan(
        const int* __restrict__ goal, const int* __restrict__ stem,
        const float* __restrict__ stem_emb,
        const s16* __restrict__ w_hi, const s16* __restrict__ w_lo,
        const float* __restrict__ b_hh, const float* __restrict__ gi_tok,
        unsigned* __restrict__ spk0, unsigned* __restrict__ spk1,
        float* __restrict__ hs, unsigned* bar) {
    __shared__ s16 wlds[96 * 512];   // 96 KB, viewed as [6][16][64][8]
    const int tid = threadIdx.x;
    const int wg = blockIdx.x;
    const int c = wg & 7;
    const int jt = wg >> 3;
    const int w = tid >> 6;
    const int l = tid & 63;
    const int ln = l & 15;
    const int kg = l >> 4;
    const int row0 = c * 32 + w * 16;   // this wave's 16 batch rows
    const int j = jt * 16 + ln;

    // one-time: stage weight slice into LDS, fragment-major.
    for (int i = tid; i < 6144; i += 128) {
        int lane = i & 63;
        int chunk = i >> 6;           // 0..95 = g2*16 + kcIdx
        int g2 = chunk >> 4;          // gate*2 + hl
        int kcIdx = chunk & 15;
        int gate = g2 >> 1, hl = g2 & 1;
        int lnn = lane & 15, kgg = lane >> 4;
        const s16* src = (hl ? w_lo : w_hi) +
                         ((size_t)(gate * H + jt * 16 + lnn)) * H + kcIdx * 32 + kgg * 8;
        *(s16x8*)(wlds + (size_t)i * 8) = *(const s16x8*)src;
    }
    // one-time: h0 split (packed) for this cluster's rows; WG jt inits row c*32+jt
    {
        int b = c * 32 + jt;
        int c4 = tid;                 // 0..127 float4s
        float4 v = ((const float4*)(stem_emb + (size_t)stem[b] * H))[c4];
        float xs[4] = {v.x, v.y, v.z, v.w};
        #pragma unroll
        for (int q = 0; q < 4; ++q)
            __hip_atomic_store(spk0 + (size_t)b * H + c4 * 4 + q, packsplit(xs[q]),
                               __ATOMIC_RELAXED, __HIP_MEMORY_SCOPE_AGENT);
    }
    // hprev in registers: exact h0 at this lane's (b, j) positions
    float hprev[4];
    #pragma unroll
    for (int q = 0; q < 4; ++q) {
        int b = row0 + kg * 4 + q;
        hprev[q] = stem_emb[(size_t)stem[b] * H + j];
    }
    clusterbar(bar, c, 1u, tid);

    const float bhr = b_hh[j], bhz = b_hh[H + j], bhn = b_hh[2 * H + j];

    for (int t = 0; t <= L; ++t) {
        unsigned* pin = (t & 1) ? spk1 : spk0;
        unsigned* pout = (t & 1) ? spk0 : spk1;
        float* h_out = (t < L) ? (hs + (size_t)(t + 1) * SLOT) : hs;  // EOS -> slot 0

        const u64* ap = (const u64*)pin + (size_t)(row0 + ln) * (H / 2) + kg * 4;

        // token + gi prefetch (normal cached loads; drained by the waitcnt below)
        int bq[4];
        float g0[4], g1[4], g2v[4];
        #pragma unroll
        for (int q = 0; q < 4; ++q) {
            bq[q] = row0 + kg * 4 + q;
            int v = (t < L) ? goal[(size_t)bq[q] * L + t] : EOS_TOK;
            const float* gi = gi_tok + (size_t)v * H3;
            g0[q] = gi[j];
            g1[q] = gi[H + j];
            g2v[q] = gi[2 * H + j];
        }

        // batch-issue ALL 64 A-loads (volatile asm: ordered, all results live)
        u64 av[64];
        LoadAll<0>::run(ap, av);
        asm volatile("s_waitcnt vmcnt(0)" ::: "memory");
        __builtin_amdgcn_sched_barrier(0);

        f32x4v ar{}, az{}, an{};
        #pragma unroll
        for (int kcIdx = 0; kcIdx < 16; ++kcIdx) {
            s16x8 Ah, Al;
            #pragma unroll
            for (int i = 0; i < 4; ++i) {
                u64 wv = av[kcIdx * 4 + i];
                unsigned lo32 = (unsigned)wv, hi32 = (unsigned)(wv >> 32);
                Ah[2 * i]     = (s16)(lo32 & 0xffff);
                Al[2 * i]     = (s16)(lo32 >> 16);
                Ah[2 * i + 1] = (s16)(hi32 & 0xffff);
                Al[2 * i + 1] = (s16)(hi32 >> 16);
            }
            const s16* bb = wlds + ((size_t)(kcIdx * 64 + l)) * 8;
            s16x8 Rh = *(const s16x8*)(bb);
            s16x8 Rl = *(const s16x8*)(bb + 8192);
            s16x8 Zh = *(const s16x8*)(bb + 16384);
            s16x8 Zl = *(const s16x8*)(bb + 24576);
            s16x8 Nh = *(const s16x8*)(bb + 32768);
            s16x8 Nl = *(const s16x8*)(bb + 40960);
            ar = __builtin_amdgcn_mfma_f32_16x16x32_bf16(Ah, Rh, ar, 0, 0, 0);
            az = __builtin_amdgcn_mfma_f32_16x16x32_bf16(Ah, Zh, az, 0, 0, 0);
            an = __builtin_amdgcn_mfma_f32_16x16x32_bf16(Ah, Nh, an, 0, 0, 0);
            ar = __builtin_amdgcn_mfma_f32_16x16x32_bf16(Ah, Rl, ar, 0, 0, 0);
            az = __builtin_amdgcn_mfma_f32_16x16x32_bf16(Ah, Zl, az, 0, 0, 0);
            an = __builtin_amdgcn_mfma_f32_16x16x32_bf16(Ah, Nl, an, 0, 0, 0);
            ar = __builtin_amdgcn_mfma_f32_16x16x32_bf16(Al, Rh, ar, 0, 0, 0);
            az = __builtin_amdgcn_mfma_f32_16x16x32_bf16(Al, Zh, az, 0, 0, 0);
            an = __builtin_amdgcn_mfma_f32_16x16x32_bf16(Al, Nh, an, 0, 0, 0);
        }

        #pragma unroll
        for (int q = 0; q < 4; ++q) {
            float r = sigmoidf_(g0[q] + ar[q] + bhr);
            float z = sigmoidf_(g1[q] + az[q] + bhz);
            float x = g2v[q] + r * (an[q] + bhn);
            float e = __expf(-2.f * x);
            float nn = (1.f - e) / (1.f + e);         // tanh(x)
            float hn = (1.f - z) * nn + z * hprev[q];
            hprev[q] = hn;
            __builtin_nontemporal_store(hn, h_out + (size_t)bq[q] * H + j);
            __hip_atomic_store(pout + (size_t)bq[q] * H + j, packsplit(hn),
                               __ATOMIC_RELAXED, __HIP_MEMORY_SCOPE_AGENT);
        }

        if (t < L) clusterbar(bar, c, (unsigned)(t + 2), tid);
    }
}

// ---------------- fused MLP via MFMA ----------------
__global__ __launch_bounds__(256, 1) void k_mlp_mfma(
        const float* __restrict__ states,
        const s16* __restrict__ w0h, const s16* __restrict__ w0l,
        const float* __restrict__ b0v,
        const s16* __restrict__ w1h, const s16* __restrict__ w1l,
        const float* __restrict__ b1v,
        const float* __restrict__ w2v, const float* __restrict__ b2v,
        float* __restrict__ out, int col0) {
    __shared__ float v1s[64 * 512];   // 128 KB
    __shared__ float red[4][64];
    const int tid = threadIdx.x;
    const int wid = tid >> 6;
    const int l = tid & 63;
    const int ln = l & 15;
    const int kg = l >> 4;
    const int r0 = blockIdx.x * 64;
    const int col = col0 + (r0 >> 8);
    const int b0 = r0 & 255;

    f32x4v acc[4][8];
    #pragma unroll
    for (int mf = 0; mf < 4; ++mf)
        #pragma unroll
        for (int nf = 0; nf < 8; ++nf) acc[mf][nf] = f32x4v{};

    // ---- GEMM1: v1 = relu(relu(h) @ w0.T + b0) ----
    for (int kc = 0; kc < H; kc += 32) {
        s16x8 Ah[4], Al[4];
        #pragma unroll
        for (int mf = 0; mf < 4; ++mf) {
            const float* ap = states + (size_t)(r0 + mf * 16 + ln) * H + kc + kg * 8;
            float4 x0 = *(const float4*)ap;
            float4 x1 = *(const float4*)(ap + 4);
            float y[8] = {fmaxf(x0.x,0.f), fmaxf(x0.y,0.f), fmaxf(x0.z,0.f), fmaxf(x0.w,0.f),
                          fmaxf(x1.x,0.f), fmaxf(x1.y,0.f), fmaxf(x1.z,0.f), fmaxf(x1.w,0.f)};
            #pragma unroll
            for (int i = 0; i < 8; ++i) {
                s16 hh = f2bf(y[i]);
                Ah[mf][i] = hh;
                Al[mf][i] = f2bf(y[i] - bf2f(hh));
            }
        }
        #pragma unroll
        for (int nf = 0; nf < 8; ++nf) {
            const int n = wid * 128 + nf * 16 + ln;
            s16x8 Bh = *(const s16x8*)(w0h + (size_t)n * H + kc + kg * 8);
            s16x8 Bl = *(const s16x8*)(w0l + (size_t)n * H + kc + kg * 8);
            #pragma unroll
            for (int mf = 0; mf < 4; ++mf) {
                acc[mf][nf] = __builtin_amdgcn_mfma_f32_16x16x32_bf16(Ah[mf], Bh, acc[mf][nf], 0, 0, 0);
                acc[mf][nf] = __builtin_amdgcn_mfma_f32_16x16x32_bf16(Ah[mf], Bl, acc[mf][nf], 0, 0, 0);
                acc[mf][nf] = __builtin_amdgcn_mfma_f32_16x16x32_bf16(Al[mf], Bh, acc[mf][nf], 0, 0, 0);
            }
        }
    }
    float bn[8];
    #pragma unroll
    for (int nf = 0; nf < 8; ++nf) bn[nf] = b0v[wid * 128 + nf * 16 + ln];
    #pragma unroll
    for (int mf = 0; mf < 4; ++mf)
        #pragma unroll
        for (int nf = 0; nf < 8; ++nf)
            #pragma unroll
            for (int q = 0; q < 4; ++q) {
                int m = mf * 16 + kg * 4 + q;
                int n = wid * 128 + nf * 16 + ln;
                v1s[m * 512 + (n ^ ((m & 7) << 2))] = fmaxf(acc[mf][nf][q] + bn[nf], 0.f);
            }
    __syncthreads();

    // ---- GEMM2: v2 = relu(v1 @ w1.T + b1); lik = v2 . w2 ----
    #pragma unroll
    for (int mf = 0; mf < 4; ++mf)
        #pragma unroll
        for (int nf = 0; nf < 8; ++nf) acc[mf][nf] = f32x4v{};
    for (int kc = 0; kc < H; kc += 32) {
        s16x8 Ah[4], Al[4];
        #pragma unroll
        for (int mf = 0; mf < 4; ++mf) {
            const int rr = mf * 16 + ln;
            const int cx = (rr & 7) << 2;
            const int k0 = kc + kg * 8;
            float4 y0 = *(const float4*)(v1s + rr * 512 + (k0 ^ cx));
            float4 y1 = *(const float4*)(v1s + rr * 512 + ((k0 + 4) ^ cx));
            float y[8] = {y0.x, y0.y, y0.z, y0.w, y1.x, y1.y, y1.z, y1.w};
            #pragma unroll
            for (int i = 0; i < 8; ++i) {
                s16 hh = f2bf(y[i]);
                Ah[mf][i] = hh;
                Al[mf][i] = f2bf(y[i] - bf2f(hh));
            }
        }
        #pragma unroll
        for (int nf = 0; nf < 8; ++nf) {
            const int n = wid * 128 + nf * 16 + ln;
            s16x8 Bh = *(const s16x8*)(w1h + (size_t)n * H + kc + kg * 8);
            s16x8 Bl = *(const s16x8*)(w1l + (size_t)n * H + kc + kg * 8);
            #pragma unroll
            for (int mf = 0; mf < 4; ++mf) {
                acc[mf][nf] = __builtin_amdgcn_mfma_f32_16x16x32_bf16(Ah[mf], Bh, acc[mf][nf], 0, 0, 0);
                acc[mf][nf] = __builtin_amdgcn_mfma_f32_16x16x32_bf16(Ah[mf], Bl, acc[mf][nf], 0, 0, 0);
                acc[mf][nf] = __builtin_amdgcn_mfma_f32_16x16x32_bf16(Al[mf], Bh, acc[mf][nf], 0, 0, 0);
            }
        }
    }
    float b1n[8], w2n[8];
    #pragma unroll
    for (int nf = 0; nf < 8; ++nf) {
        int n = wid * 128 + nf * 16 + ln;
        b1n[nf] = b1v[n];
        w2n[nf] = w2v[n];
    }
    float psum[4][4];
    #pragma unroll
    for (int mf = 0; mf < 4; ++mf)
        #pragma unroll
        for (int q = 0; q < 4; ++q) {
            float s = 0.f;
            #pragma unroll
            for (int nf = 0; nf < 8; ++nf)
                s += fmaxf(acc[mf][nf][q] + b1n[nf], 0.f) * w2n[nf];
            psum[mf][q] = s;
        }
    #pragma unroll
    for (int mf = 0; mf < 4; ++mf)
        #pragma unroll
        for (int q = 0; q < 4; ++q) {
            float s = psum[mf][q];
            #pragma unroll
            for (int msk = 1; msk < 16; msk <<= 1)
                s += __shfl_xor(s, msk, 64);
            psum[mf][q] = s;
        }
    if (ln == 0) {
        #pragma unroll
        for (int mf = 0; mf < 4; ++mf)
            #pragma unroll
            for (int q = 0; q < 4; ++q)
                red[wid][mf * 16 + kg * 4 + q] = psum[mf][q];
    }
    __syncthreads();
    if (tid < 64) {
        float s = b2v[0] + red[0][tid] + red[1][tid] + red[2][tid] + red[3][tid];
        out[(size_t)(b0 + tid) * OUTC + col] = s;
    }
}

extern "C" void kernel_launch(void* const* d_in, const int* in_sizes, int n_in,
                              void* d_out, int out_size, void* d_ws, size_t ws_size,
                              hipStream_t stream) {
    (void)in_sizes; (void)n_in; (void)out_size; (void)ws_size;
    const int* stem = (const int*)d_in[0];
    const int* goal = (const int*)d_in[1];
    const float* stem_emb = (const float*)d_in[2];
    const float* token_emb = (const float*)d_in[3];
    const float* w_ih = (const float*)d_in[4];
    const float* w_hh = (const float*)d_in[5];
    const float* b_ih = (const float*)d_in[6];
    const float* b_hh = (const float*)d_in[7];
    const float* w0 = (const float*)d_in[8];
    const float* b0 = (const float*)d_in[9];
    const float* w1 = (const float*)d_in[10];
    const float* b1 = (const float*)d_in[11];
    const float* w2 = (const float*)d_in[12];
    const float* b2 = (const float*)d_in[13];
    float* out = (float*)d_out;

    char* p = (char*)d_ws;
    float* gi_tok = (float*)p;      p += (size_t)TOKV * H3 * 4;
    s16* whh_h = (s16*)p;           p += (size_t)H3 * H * 2;
    s16* whh_l = (s16*)p;           p += (size_t)H3 * H * 2;
    s16* w0h = (s16*)p;             p += (size_t)H * H * 2;
    s16* w0l = (s16*)p;             p += (size_t)H * H * 2;
    s16* w1h = (s16*)p;             p += (size_t)H * H * 2;
    s16* w1l = (s16*)p;             p += (size_t)H * H * 2;
    unsigned* spk0 = (unsigned*)p;  p += SLOT * 4;
    unsigned* spk1 = (unsigned*)p;  p += SLOT * 4;
    unsigned* bar = (unsigned*)p;   p += 4096;
    float* hs = (float*)p;          // 257 slots: [1..256]=post-step states, [0]=EOS final

    hipMemsetAsync(bar, 0, 4096, stream);

    // prep
    k_split<<<768, 256, 0, stream>>>(w_hh, whh_h, whh_l, H3 * H / 4);
    k_split<<<256, 256, 0, stream>>>(w0, w0h, w0l, H * H / 4);
    k_split<<<256, 256, 0, stream>>>(w1, w1h, w1l, H * H / 4);
    k_gi_tok<<<128, 256, 0, stream>>>(token_emb, w_ih, b_ih, gi_tok);

    // persistent clustered scan (h0 init + 256 GRU steps + EOS step)
    {
        const int* goal_a = goal;
        const int* stem_a = stem;
        const float* stem_emb_a = stem_emb;
        const s16* whh_h_a = whh_h;
        const s16* whh_l_a = whh_l;
        const float* b_hh_a = b_hh;
        const float* gi_tok_a = gi_tok;
        unsigned* spk0_a = spk0;
        unsigned* spk1_a = spk1;
        float* hs_a = hs;
        unsigned* bar_a = bar;
        void* kargs[] = {(void*)&goal_a, (void*)&stem_a, (void*)&stem_emb_a,
                         (void*)&whh_h_a, (void*)&whh_l_a, (void*)&b_hh_a,
                         (void*)&gi_tok_a, (void*)&spk0_a, (void*)&spk1_a,
                         (void*)&hs_a, (void*)&bar_a};
        hipLaunchCooperativeKernel((void*)k_scan, dim3(256), dim3(128),
                                   kargs, 0, stream);
    }

    // MLP: cols 1..256 from hs[1..256], col 0 (EOS) from hs[0]
    k_mlp_mfma<<<1024, 256, 0, stream>>>(hs + SLOT, w0h, w0l, b0,
                                         w1h, w1l, b1, w2, b2, out, 1);
    k_mlp_mfma<<<4, 256, 0, stream>>>(hs, w0h, w0l, b0,
                                      w1h, w1l, b1, w2, b2, out, 0);
}

// Round 11
// 2456.470 us; speedup vs baseline: 1.0209x; 1.0209x over previous
//
#include <hip/hip_runtime.h>
#include <math.h>

#define B 256
#define L 256
#define H 512
#define H3 1536
#define TOKV 128
#define EOS_TOK 1
#define OUTC 257
#define SLOT ((size_t)B * H)   // elements per h-state

typedef short s16;
typedef s16 s16x8 __attribute__((ext_vector_type(8)));
typedef s16 s16x4 __attribute__((ext_vector_type(4)));
typedef float f32x4v __attribute__((ext_vector_type(4)));
typedef unsigned long long u64;

__device__ __forceinline__ float sigmoidf_(float x) {
    return 1.0f / (1.0f + __expf(-x));
}

// fp32 -> bf16 bit pattern, round-to-nearest-even (same as (__bf16) cast)
__device__ __forceinline__ s16 f2bf(float x) {
    unsigned u = __builtin_bit_cast(unsigned, x);
    u += 0x7fffu + ((u >> 16) & 1u);
    return (s16)(u >> 16);
}
__device__ __forceinline__ float bf2f(s16 h) {
    return __builtin_bit_cast(float, ((unsigned)(unsigned short)h) << 16);
}
// pack hi(low16)|lo(high16) of a float's 2-term bf16 split
__device__ __forceinline__ unsigned packsplit(float x) {
    s16 hh = f2bf(x);
    s16 ll = f2bf(x - bf2f(hh));
    return (unsigned)(unsigned short)hh | ((unsigned)(unsigned short)ll << 16);
}

// device-scope (sc1) 8B load with immediate offset, volatile-ordered.
template<int BOFF>
__device__ __forceinline__ u64 gld_sc1(const u64* base) {
    u64 d;
    asm volatile("global_load_dwordx2 %0, %1, off offset:%2 sc1"
                 : "=v"(d) : "v"(base), "n"(BOFF));
    return d;
}
// batch-issue 64 loads (16 k-chunks x 4), offsets kc*128 + ii*8 bytes
template<int KC>
struct LoadAll {
    static __device__ __forceinline__ void run(const u64* base, u64* dst) {
        dst[KC * 4 + 0] = gld_sc1<KC * 128 + 0>(base);
        dst[KC * 4 + 1] = gld_sc1<KC * 128 + 8>(base);
        dst[KC * 4 + 2] = gld_sc1<KC * 128 + 16>(base);
        dst[KC * 4 + 3] = gld_sc1<KC * 128 + 24>(base);
        LoadAll<KC + 1>::run(base, dst);
    }
};
template<>
struct LoadAll<16> {
    static __device__ __forceinline__ void run(const u64*, u64*) {}
};

// ---------------- per-cluster barrier (monotonic, relaxed + compiler fences) ----------------
// Proven in R6/R7/R9. Data flows via sc1 ops; barrier uses contended RMW on
// one counter per cluster. Counters zeroed per launch -> replay-deterministic.
__device__ __forceinline__ void clusterbar(unsigned* bar, int c, unsigned n, int tid) {
    __syncthreads();
    if (tid == 0) {
        const unsigned tgt = 32u * n;
        unsigned* ctr = bar + c * 32;
        asm volatile("" ::: "memory");
        __hip_atomic_fetch_add(ctr, 1u, __ATOMIC_RELAXED, __HIP_MEMORY_SCOPE_AGENT);
        while (__hip_atomic_load(ctr, __ATOMIC_RELAXED, __HIP_MEMORY_SCOPE_AGENT) < tgt)
            __builtin_amdgcn_s_sleep(1);
        asm volatile("" ::: "memory");
    }
    __syncthreads();
}

// ---------------- prep: elementwise split of a fp32 weight array ----------------
__global__ __launch_bounds__(256) void k_split(const float* __restrict__ src,
                                               s16* __restrict__ hi,
                                               s16* __restrict__ lo, int n4) {
    int i = blockIdx.x * 256 + threadIdx.x;
    if (i >= n4) return;
    float4 x = ((const float4*)src)[i];
    float xs[4] = {x.x, x.y, x.z, x.w};
    s16x4 h, l;
    #pragma unroll
    for (int q = 0; q < 4; ++q) {
        s16 hh = f2bf(xs[q]);
        h[q] = hh;
        l[q] = f2bf(xs[q] - bf2f(hh));
    }
    *(s16x4*)(hi + (size_t)i * 4) = h;
    *(s16x4*)(lo + (size_t)i * 4) = l;
}

// ---------------- prep: gi_tok[v][j] = relu(token_emb[v]) . w_ih[j] + b_ih[j] (fp32) ----------------
__global__ __launch_bounds__(256) void k_gi_tok(
        const float* __restrict__ token_emb, const float* __restrict__ w_ih,
        const float* __restrict__ b_ih, float* __restrict__ gi_out) {
    __shared__ float wlds[96][132];
    __shared__ float elds[16][132];
    const int vi = blockIdx.x >> 4;
    const int ji = blockIdx.x & 15;
    const int v0 = vi << 4, j0 = ji * 96;
    const int tid = threadIdx.x;
    const int vl = tid & 7;
    const int jl = tid >> 3;
    float acc[2][3] = {{0.f, 0.f, 0.f}, {0.f, 0.f, 0.f}};
    for (int ck = 0; ck < 4; ++ck) {
        const int c0 = ck << 7;
        __syncthreads();
        for (int i = tid; i < 96 * 32; i += 256) {
            int row = i >> 5, c4 = i & 31;
            *(float4*)&wlds[row][c4 << 2] =
                *(const float4*)(w_ih + (size_t)(j0 + row) * H + c0 + (c4 << 2));
        }
        for (int i = tid; i < 16 * 32; i += 256) {
            int row = i >> 5, c4 = i & 31;
            float4 e = *(const float4*)(token_emb + (size_t)(v0 + row) * H + c0 + (c4 << 2));
            e.x = fmaxf(e.x, 0.f); e.y = fmaxf(e.y, 0.f);
            e.z = fmaxf(e.z, 0.f); e.w = fmaxf(e.w, 0.f);
            *(float4*)&elds[row][c4 << 2] = e;
        }
        __syncthreads();
        #pragma unroll 8
        for (int c = 0; c < 128; c += 4) {
            float4 wa = *(const float4*)&wlds[jl][c];
            float4 wb = *(const float4*)&wlds[32 + jl][c];
            float4 wc = *(const float4*)&wlds[64 + jl][c];
            float4 ea = *(const float4*)&elds[vl][c];
            float4 eb = *(const float4*)&elds[vl + 8][c];
            acc[0][0] += ea.x*wa.x + ea.y*wa.y + ea.z*wa.z + ea.w*wa.w;
            acc[0][1] += ea.x*wb.x + ea.y*wb.y + ea.z*wb.z + ea.w*wb.w;
            acc[0][2] += ea.x*wc.x + ea.y*wc.y + ea.z*wc.z + ea.w*wc.w;
            acc[1][0] += eb.x*wa.x + eb.y*wa.y + eb.z*wa.z + eb.w*wa.w;
            acc[1][1] += eb.x*wb.x + eb.y*wb.y + eb.z*wb.z + eb.w*wb.w;
            acc[1][2] += eb.x*wc.x + eb.y*wc.y + eb.z*wc.z + eb.w*wc.w;
        }
    }
    #pragma unroll
    for (int p = 0; p < 2; ++p) {
        int v = v0 + vl + (p << 3);
        #pragma unroll
        for (int s = 0; s < 3; ++s) {
            int j = j0 + (s << 5) + jl;
            gi_out[(size_t)v * H3 + j] = acc[p][s] + b_ih[j];
        }
    }
}

// ---------------- persistent GRU scan, clustered (cooperative, 256 WGs x 128 thr) ----------------
// Identical to the R9-proven kernel except the hs store: states for the MLP
// are stored PACKED-RELU-SPLIT (u32 = bf16hi | bf16lo<<16 of relu(h)) — same
// store instruction/width/position, different value. No sync changes.
__global__ __launch_bounds__(128, 1) void k_scan(
        const int* __restrict__ goal, const int* __restrict__ stem,
        const float* __restrict__ stem_emb,
        const s16* __restrict__ w_hi, const s16* __restrict__ w_lo,
        const float* __restrict__ b_hh, const float* __restrict__ gi_tok,
        unsigned* __restrict__ spk0, unsigned* __restrict__ spk1,
        unsigned* __restrict__ hsp, unsigned* bar) {
    __shared__ s16 wlds[96 * 512];   // 96 KB, viewed as [6][16][64][8]
    const int tid = threadIdx.x;
    const int wg = blockIdx.x;
    const int c = wg & 7;
    const int jt = wg >> 3;
    const int w = tid >> 6;
    const int l = tid & 63;
    const int ln = l & 15;
    const int kg = l >> 4;
    const int row0 = c * 32 + w * 16;   // this wave's 16 batch rows
    const int j = jt * 16 + ln;

    // one-time: stage weight slice into LDS, fragment-major.
    for (int i = tid; i < 6144; i += 128) {
        int lane = i & 63;
        int chunk = i >> 6;           // 0..95 = g2*16 + kcIdx
        int g2 = chunk >> 4;          // gate*2 + hl
        int kcIdx = chunk & 15;
        int gate = g2 >> 1, hl = g2 & 1;
        int lnn = lane & 15, kgg = lane >> 4;
        const s16* src = (hl ? w_lo : w_hi) +
                         ((size_t)(gate * H + jt * 16 + lnn)) * H + kcIdx * 32 + kgg * 8;
        *(s16x8*)(wlds + (size_t)i * 8) = *(const s16x8*)src;
    }
    // one-time: h0 split (packed) for this cluster's rows; WG jt inits row c*32+jt
    {
        int b = c * 32 + jt;
        int c4 = tid;                 // 0..127 float4s
        float4 v = ((const float4*)(stem_emb + (size_t)stem[b] * H))[c4];
        float xs[4] = {v.x, v.y, v.z, v.w};
        #pragma unroll
        for (int q = 0; q < 4; ++q)
            __hip_atomic_store(spk0 + (size_t)b * H + c4 * 4 + q, packsplit(xs[q]),
                               __ATOMIC_RELAXED, __HIP_MEMORY_SCOPE_AGENT);
    }
    // hprev in registers: exact h0 at this lane's (b, j) positions
    float hprev[4];
    #pragma unroll
    for (int q = 0; q < 4; ++q) {
        int b = row0 + kg * 4 + q;
        hprev[q] = stem_emb[(size_t)stem[b] * H + j];
    }
    clusterbar(bar, c, 1u, tid);

    const float bhr = b_hh[j], bhz = b_hh[H + j], bhn = b_hh[2 * H + j];

    for (int t = 0; t <= L; ++t) {
        unsigned* pin = (t & 1) ? spk1 : spk0;
        unsigned* pout = (t & 1) ? spk0 : spk1;
        unsigned* h_out = (t < L) ? (hsp + (size_t)(t + 1) * SLOT) : hsp;  // EOS -> slot 0

        const u64* ap = (const u64*)pin + (size_t)(row0 + ln) * (H / 2) + kg * 4;

        // token + gi prefetch (normal cached loads; drained by the waitcnt below)
        int bq[4];
        float g0[4], g1[4], g2v[4];
        #pragma unroll
        for (int q = 0; q < 4; ++q) {
            bq[q] = row0 + kg * 4 + q;
            int v = (t < L) ? goal[(size_t)bq[q] * L + t] : EOS_TOK;
            const float* gi = gi_tok + (size_t)v * H3;
            g0[q] = gi[j];
            g1[q] = gi[H + j];
            g2v[q] = gi[2 * H + j];
        }

        // batch-issue ALL 64 A-loads (volatile asm: ordered, all results live)
        u64 av[64];
        LoadAll<0>::run(ap, av);
        asm volatile("s_waitcnt vmcnt(0)" ::: "memory");
        __builtin_amdgcn_sched_barrier(0);

        f32x4v ar{}, az{}, an{};
        #pragma unroll
        for (int kcIdx = 0; kcIdx < 16; ++kcIdx) {
            s16x8 Ah, Al;
            #pragma unroll
            for (int i = 0; i < 4; ++i) {
                u64 wv = av[kcIdx * 4 + i];
                unsigned lo32 = (unsigned)wv, hi32 = (unsigned)(wv >> 32);
                Ah[2 * i]     = (s16)(lo32 & 0xffff);
                Al[2 * i]     = (s16)(lo32 >> 16);
                Ah[2 * i + 1] = (s16)(hi32 & 0xffff);
                Al[2 * i + 1] = (s16)(hi32 >> 16);
            }
            const s16* bb = wlds + ((size_t)(kcIdx * 64 + l)) * 8;
            s16x8 Rh = *(const s16x8*)(bb);
            s16x8 Rl = *(const s16x8*)(bb + 8192);
            s16x8 Zh = *(const s16x8*)(bb + 16384);
            s16x8 Zl = *(const s16x8*)(bb + 24576);
            s16x8 Nh = *(const s16x8*)(bb + 32768);
            s16x8 Nl = *(const s16x8*)(bb + 40960);
            ar = __builtin_amdgcn_mfma_f32_16x16x32_bf16(Ah, Rh, ar, 0, 0, 0);
            az = __builtin_amdgcn_mfma_f32_16x16x32_bf16(Ah, Zh, az, 0, 0, 0);
            an = __builtin_amdgcn_mfma_f32_16x16x32_bf16(Ah, Nh, an, 0, 0, 0);
            ar = __builtin_amdgcn_mfma_f32_16x16x32_bf16(Ah, Rl, ar, 0, 0, 0);
            az = __builtin_amdgcn_mfma_f32_16x16x32_bf16(Ah, Zl, az, 0, 0, 0);
            an = __builtin_amdgcn_mfma_f32_16x16x32_bf16(Ah, Nl, an, 0, 0, 0);
            ar = __builtin_amdgcn_mfma_f32_16x16x32_bf16(Al, Rh, ar, 0, 0, 0);
            az = __builtin_amdgcn_mfma_f32_16x16x32_bf16(Al, Zh, az, 0, 0, 0);
            an = __builtin_amdgcn_mfma_f32_16x16x32_bf16(Al, Nh, an, 0, 0, 0);
        }

        #pragma unroll
        for (int q = 0; q < 4; ++q) {
            float r = sigmoidf_(g0[q] + ar[q] + bhr);
            float z = sigmoidf_(g1[q] + az[q] + bhz);
            float x = g2v[q] + r * (an[q] + bhn);
            float e = __expf(-2.f * x);
            float nn = (1.f - e) / (1.f + e);         // tanh(x)
            float hn = (1.f - z) * nn + z * hprev[q];
            hprev[q] = hn;
            __builtin_nontemporal_store(packsplit(fmaxf(hn, 0.f)),
                                        h_out + (size_t)bq[q] * H + j);
            __hip_atomic_store(pout + (size_t)bq[q] * H + j, packsplit(hn),
                               __ATOMIC_RELAXED, __HIP_MEMORY_SCOPE_AGENT);
        }

        if (t < L) clusterbar(bar, c, (unsigned)(t + 2), tid);
    }
}

// ---------------- fused MLP via MFMA (packed-split-relu states; packed v1 in LDS) ----------------
__global__ __launch_bounds__(256, 1) void k_mlp_mfma(
        const unsigned* __restrict__ statesp,
        const s16* __restrict__ w0h, const s16* __restrict__ w0l,
        const float* __restrict__ b0v,
        const s16* __restrict__ w1h, const s16* __restrict__ w1l,
        const float* __restrict__ b1v,
        const float* __restrict__ w2v, const float* __restrict__ b2v,
        float* __restrict__ out, int col0) {
    __shared__ unsigned v1s[64 * 512];   // 128 KB, packed-split v1
    __shared__ float red[4][64];
    const int tid = threadIdx.x;
    const int wid = tid >> 6;
    const int l = tid & 63;
    const int ln = l & 15;
    const int kg = l >> 4;
    const int r0 = blockIdx.x * 64;
    const int col = col0 + (r0 >> 8);
    const int b0 = r0 & 255;

    f32x4v acc[4][8];
    #pragma unroll
    for (int mf = 0; mf < 4; ++mf)
        #pragma unroll
        for (int nf = 0; nf < 8; ++nf) acc[mf][nf] = f32x4v{};

    // ---- GEMM1: v1 = relu(y @ w0.T + b0), y pre-packed-relu ----
    for (int kc = 0; kc < H; kc += 32) {
        s16x8 Ah[4], Al[4];
        #pragma unroll
        for (int mf = 0; mf < 4; ++mf) {
            const unsigned* ap = statesp + (size_t)(r0 + mf * 16 + ln) * H + kc + kg * 8;
            uint4 p0 = *(const uint4*)ap;
            uint4 p1 = *(const uint4*)(ap + 4);
            unsigned pv[8] = {p0.x, p0.y, p0.z, p0.w, p1.x, p1.y, p1.z, p1.w};
            #pragma unroll
            for (int i = 0; i < 8; ++i) {
                Ah[mf][i] = (s16)(pv[i] & 0xffff);
                Al[mf][i] = (s16)(pv[i] >> 16);
            }
        }
        #pragma unroll
        for (int nf = 0; nf < 8; ++nf) {
            const int n = wid * 128 + nf * 16 + ln;
            s16x8 Bh = *(const s16x8*)(w0h + (size_t)n * H + kc + kg * 8);
            s16x8 Bl = *(const s16x8*)(w0l + (size_t)n * H + kc + kg * 8);
            #pragma unroll
            for (int mf = 0; mf < 4; ++mf) {
                acc[mf][nf] = __builtin_amdgcn_mfma_f32_16x16x32_bf16(Ah[mf], Bh, acc[mf][nf], 0, 0, 0);
                acc[mf][nf] = __builtin_amdgcn_mfma_f32_16x16x32_bf16(Ah[mf], Bl, acc[mf][nf], 0, 0, 0);
                acc[mf][nf] = __builtin_amdgcn_mfma_f32_16x16x32_bf16(Al[mf], Bh, acc[mf][nf], 0, 0, 0);
            }
        }
    }
    float bn[8];
    #pragma unroll
    for (int nf = 0; nf < 8; ++nf) bn[nf] = b0v[wid * 128 + nf * 16 + ln];
    #pragma unroll
    for (int mf = 0; mf < 4; ++mf)
        #pragma unroll
        for (int nf = 0; nf < 8; ++nf)
            #pragma unroll
            for (int q = 0; q < 4; ++q) {
                int m = mf * 16 + kg * 4 + q;
                int n = wid * 128 + nf * 16 + ln;
                v1s[m * 512 + (n ^ ((m & 7) << 2))] = packsplit(fmaxf(acc[mf][nf][q] + bn[nf], 0.f));
            }
    __syncthreads();

    // ---- GEMM2: v2 = relu(v1 @ w1.T + b1); lik = v2 . w2 ----
    #pragma unroll
    for (int mf = 0; mf < 4; ++mf)
        #pragma unroll
        for (int nf = 0; nf < 8; ++nf) acc[mf][nf] = f32x4v{};
    for (int kc = 0; kc < H; kc += 32) {
        s16x8 Ah[4], Al[4];
        #pragma unroll
        for (int mf = 0; mf < 4; ++mf) {
            const int rr = mf * 16 + ln;
            const int cx = (rr & 7) << 2;
            const int k0 = kc + kg * 8;
            uint4 p0 = *(const uint4*)(v1s + rr * 512 + (k0 ^ cx));
            uint4 p1 = *(const uint4*)(v1s + rr * 512 + ((k0 + 4) ^ cx));
            unsigned pv[8] = {p0.x, p0.y, p0.z, p0.w, p1.x, p1.y, p1.z, p1.w};
            #pragma unroll
            for (int i = 0; i < 8; ++i) {
                Ah[mf][i] = (s16)(pv[i] & 0xffff);
                Al[mf][i] = (s16)(pv[i] >> 16);
            }
        }
        #pragma unroll
        for (int nf = 0; nf < 8; ++nf) {
            const int n = wid * 128 + nf * 16 + ln;
            s16x8 Bh = *(const s16x8*)(w1h + (size_t)n * H + kc + kg * 8);
            s16x8 Bl = *(const s16x8*)(w1l + (size_t)n * H + kc + kg * 8);
            #pragma unroll
            for (int mf = 0; mf < 4; ++mf) {
                acc[mf][nf] = __builtin_amdgcn_mfma_f32_16x16x32_bf16(Ah[mf], Bh, acc[mf][nf], 0, 0, 0);
                acc[mf][nf] = __builtin_amdgcn_mfma_f32_16x16x32_bf16(Ah[mf], Bl, acc[mf][nf], 0, 0, 0);
                acc[mf][nf] = __builtin_amdgcn_mfma_f32_16x16x32_bf16(Al[mf], Bh, acc[mf][nf], 0, 0, 0);
            }
        }
    }
    float b1n[8], w2n[8];
    #pragma unroll
    for (int nf = 0; nf < 8; ++nf) {
        int n = wid * 128 + nf * 16 + ln;
        b1n[nf] = b1v[n];
        w2n[nf] = w2v[n];
    }
    float psum[4][4];
    #pragma unroll
    for (int mf = 0; mf < 4; ++mf)
        #pragma unroll
        for (int q = 0; q < 4; ++q) {
            float s = 0.f;
            #pragma unroll
            for (int nf = 0; nf < 8; ++nf)
                s += fmaxf(acc[mf][nf][q] + b1n[nf], 0.f) * w2n[nf];
            psum[mf][q] = s;
        }
    #pragma unroll
    for (int mf = 0; mf < 4; ++mf)
        #pragma unroll
        for (int q = 0; q < 4; ++q) {
            float s = psum[mf][q];
            #pragma unroll
            for (int msk = 1; msk < 16; msk <<= 1)
                s += __shfl_xor(s, msk, 64);
            psum[mf][q] = s;
        }
    if (ln == 0) {
        #pragma unroll
        for (int mf = 0; mf < 4; ++mf)
            #pragma unroll
            for (int q = 0; q < 4; ++q)
                red[wid][mf * 16 + kg * 4 + q] = psum[mf][q];
    }
    __syncthreads();
    if (tid < 64) {
        float s = b2v[0] + red[0][tid] + red[1][tid] + red[2][tid] + red[3][tid];
        out[(size_t)(b0 + tid) * OUTC + col] = s;
    }
}

extern "C" void kernel_launch(void* const* d_in, const int* in_sizes, int n_in,
                              void* d_out, int out_size, void* d_ws, size_t ws_size,
                              hipStream_t stream) {
    (void)in_sizes; (void)n_in; (void)out_size; (void)ws_size;
    const int* stem = (const int*)d_in[0];
    const int* goal = (const int*)d_in[1];
    const float* stem_emb = (const float*)d_in[2];
    const float* token_emb = (const float*)d_in[3];
    const float* w_ih = (const float*)d_in[4];
    const float* w_hh = (const float*)d_in[5];
    const float* b_ih = (const float*)d_in[6];
    const float* b_hh = (const float*)d_in[7];
    const float* w0 = (const float*)d_in[8];
    const float* b0 = (const float*)d_in[9];
    const float* w1 = (const float*)d_in[10];
    const float* b1 = (const float*)d_in[11];
    const float* w2 = (const float*)d_in[12];
    const float* b2 = (const float*)d_in[13];
    float* out = (float*)d_out;

    char* p = (char*)d_ws;
    float* gi_tok = (float*)p;      p += (size_t)TOKV * H3 * 4;
    s16* whh_h = (s16*)p;           p += (size_t)H3 * H * 2;
    s16* whh_l = (s16*)p;           p += (size_t)H3 * H * 2;
    s16* w0h = (s16*)p;             p += (size_t)H * H * 2;
    s16* w0l = (s16*)p;             p += (size_t)H * H * 2;
    s16* w1h = (s16*)p;             p += (size_t)H * H * 2;
    s16* w1l = (s16*)p;             p += (size_t)H * H * 2;
    unsigned* spk0 = (unsigned*)p;  p += SLOT * 4;
    unsigned* spk1 = (unsigned*)p;  p += SLOT * 4;
    unsigned* bar = (unsigned*)p;   p += 4096;
    unsigned* hsp = (unsigned*)p;   // 257 packed slots: [0]=EOS, [1..256]=steps

    hipMemsetAsync(bar, 0, 4096, stream);

    // prep
    k_split<<<768, 256, 0, stream>>>(w_hh, whh_h, whh_l, H3 * H / 4);
    k_split<<<256, 256, 0, stream>>>(w0, w0h, w0l, H * H / 4);
    k_split<<<256, 256, 0, stream>>>(w1, w1h, w1l, H * H / 4);
    k_gi_tok<<<128, 256, 0, stream>>>(token_emb, w_ih, b_ih, gi_tok);

    // persistent clustered scan (h0 init + 256 GRU steps + EOS step)
    {
        const int* goal_a = goal;
        const int* stem_a = stem;
        const float* stem_emb_a = stem_emb;
        const s16* whh_h_a = whh_h;
        const s16* whh_l_a = whh_l;
        const float* b_hh_a = b_hh;
        const float* gi_tok_a = gi_tok;
        unsigned* spk0_a = spk0;
        unsigned* spk1_a = spk1;
        unsigned* hsp_a = hsp;
        unsigned* bar_a = bar;
        void* kargs[] = {(void*)&goal_a, (void*)&stem_a, (void*)&stem_emb_a,
                         (void*)&whh_h_a, (void*)&whh_l_a, (void*)&b_hh_a,
                         (void*)&gi_tok_a, (void*)&spk0_a, (void*)&spk1_a,
                         (void*)&hsp_a, (void*)&bar_a};
        hipLaunchCooperativeKernel((void*)k_scan, dim3(256), dim3(128),
                                   kargs, 0, stream);
    }

    // MLP: cols 1..256 from hsp[1..256], col 0 (EOS) from hsp[0]
    k_mlp_mfma<<<1024, 256, 0, stream>>>(hsp + SLOT, w0h, w0l, b0,
                                         w1h, w1l, b1, w2, b2, out, 1);
    k_mlp_mfma<<<4, 256, 0, stream>>>(hsp, w0h, w0l, b0,
                                      w1h, w1l, b1, w2, b2, out, 0);
}

// Round 13
// 1710.291 us; speedup vs baseline: 1.4662x; 1.4363x over previous
//
#include <hip/hip_runtime.h>
#include <math.h>

#define B 256
#define L 256
#define H 512
#define H3 1536
#define TOKV 128
#define EOS_TOK 1
#define OUTC 257
#define SLOT ((size_t)B * H)   // u32 elements per h-state slot

typedef short s16;
typedef s16 s16x8 __attribute__((ext_vector_type(8)));
typedef s16 s16x4 __attribute__((ext_vector_type(4)));
typedef float f32x4v __attribute__((ext_vector_type(4)));
typedef unsigned long long u64;

__device__ __forceinline__ float sigmoidf_(float x) {
    return 1.0f / (1.0f + __expf(-x));
}

// fp32 -> bf16 bit pattern, round-to-nearest-even (same as (__bf16) cast)
__device__ __forceinline__ s16 f2bf(float x) {
    unsigned u = __builtin_bit_cast(unsigned, x);
    u += 0x7fffu + ((u >> 16) & 1u);
    return (s16)(u >> 16);
}
__device__ __forceinline__ float bf2f(s16 h) {
    return __builtin_bit_cast(float, ((unsigned)(unsigned short)h) << 16);
}
// pack hi(low16)|lo(high16) of a float's 2-term bf16 split
__device__ __forceinline__ unsigned packsplit(float x) {
    s16 hh = f2bf(x);
    s16 ll = f2bf(x - bf2f(hh));
    return (unsigned)(unsigned short)hh | ((unsigned)(unsigned short)ll << 16);
}

// ---------------- per-cluster barrier (monotonic, relaxed + compiler fences) ----------------
// Proven in R6/R7/R9/R11. Counters zeroed per launch -> replay-deterministic.
__device__ __forceinline__ void clusterbar(unsigned* bar, int c, unsigned n, int tid) {
    __syncthreads();
    if (tid == 0) {
        const unsigned tgt = 32u * n;
        unsigned* ctr = bar + c * 32;
        asm volatile("" ::: "memory");
        __hip_atomic_fetch_add(ctr, 1u, __ATOMIC_RELAXED, __HIP_MEMORY_SCOPE_AGENT);
        while (__hip_atomic_load(ctr, __ATOMIC_RELAXED, __HIP_MEMORY_SCOPE_AGENT) < tgt)
            __builtin_amdgcn_s_sleep(1);
        asm volatile("" ::: "memory");
    }
    __syncthreads();
}

// ---------------- prep: elementwise split of a fp32 weight array ----------------
__global__ __launch_bounds__(256) void k_split(const float* __restrict__ src,
                                               s16* __restrict__ hi,
                                               s16* __restrict__ lo, int n4) {
    int i = blockIdx.x * 256 + threadIdx.x;
    if (i >= n4) return;
    float4 x = ((const float4*)src)[i];
    float xs[4] = {x.x, x.y, x.z, x.w};
    s16x4 h, l;
    #pragma unroll
    for (int q = 0; q < 4; ++q) {
        s16 hh = f2bf(xs[q]);
        h[q] = hh;
        l[q] = f2bf(xs[q] - bf2f(hh));
    }
    *(s16x4*)(hi + (size_t)i * 4) = h;
    *(s16x4*)(lo + (size_t)i * 4) = l;
}

// ---------------- prep: gi_tok[v][j] = relu(token_emb[v]) . w_ih[j] + b_ih[j] (fp32) ----------------
__global__ __launch_bounds__(256) void k_gi_tok(
        const float* __restrict__ token_emb, const float* __restrict__ w_ih,
        const float* __restrict__ b_ih, float* __restrict__ gi_out) {
    __shared__ float wlds[96][132];
    __shared__ float elds[16][132];
    const int vi = blockIdx.x >> 4;
    const int ji = blockIdx.x & 15;
    const int v0 = vi << 4, j0 = ji * 96;
    const int tid = threadIdx.x;
    const int vl = tid & 7;
    const int jl = tid >> 3;
    float acc[2][3] = {{0.f, 0.f, 0.f}, {0.f, 0.f, 0.f}};
    for (int ck = 0; ck < 4; ++ck) {
        const int c0 = ck << 7;
        __syncthreads();
        for (int i = tid; i < 96 * 32; i += 256) {
            int row = i >> 5, c4 = i & 31;
            *(float4*)&wlds[row][c4 << 2] =
                *(const float4*)(w_ih + (size_t)(j0 + row) * H + c0 + (c4 << 2));
        }
        for (int i = tid; i < 16 * 32; i += 256) {
            int row = i >> 5, c4 = i & 31;
            float4 e = *(const float4*)(token_emb + (size_t)(v0 + row) * H + c0 + (c4 << 2));
            e.x = fmaxf(e.x, 0.f); e.y = fmaxf(e.y, 0.f);
            e.z = fmaxf(e.z, 0.f); e.w = fmaxf(e.w, 0.f);
            *(float4*)&elds[row][c4 << 2] = e;
        }
        __syncthreads();
        #pragma unroll 8
        for (int c = 0; c < 128; c += 4) {
            float4 wa = *(const float4*)&wlds[jl][c];
            float4 wb = *(const float4*)&wlds[32 + jl][c];
            float4 wc = *(const float4*)&wlds[64 + jl][c];
            float4 ea = *(const float4*)&elds[vl][c];
            float4 eb = *(const float4*)&elds[vl + 8][c];
            acc[0][0] += ea.x*wa.x + ea.y*wa.y + ea.z*wa.z + ea.w*wa.w;
            acc[0][1] += ea.x*wb.x + ea.y*wb.y + ea.z*wb.z + ea.w*wb.w;
            acc[0][2] += ea.x*wc.x + ea.y*wc.y + ea.z*wc.z + ea.w*wc.w;
            acc[1][0] += eb.x*wa.x + eb.y*wa.y + eb.z*wa.z + eb.w*wa.w;
            acc[1][1] += eb.x*wb.x + eb.y*wb.y + eb.z*wb.z + eb.w*wb.w;
            acc[1][2] += eb.x*wc.x + eb.y*wc.y + eb.z*wc.z + eb.w*wc.w;
        }
    }
    #pragma unroll
    for (int p = 0; p < 2; ++p) {
        int v = v0 + vl + (p << 3);
        #pragma unroll
        for (int s = 0; s < 3; ++s) {
            int j = j0 + (s << 5) + jl;
            gi_out[(size_t)v * H3 + j] = acc[p][s] + b_ih[j];
        }
    }
}

// ---------------- persistent GRU scan, clustered (256 WGs x 128 thr) ----------------
// FRAGMENT-MAJOR exchange + state layout: per 16-row block (blk = c*2 + w),
// u64 slot f = (kc*4+ii)*64 + lane holds (row = lane&15, cols = kc*32 +
// (lane>>4)*8 + 2*ii + {0,1}) packed as u32 (bf16hi|lo<<16). Each A-load
// instruction reads 64 lanes x 8B CONTIGUOUS. hsp uses the same layout per
// slot. Sync identical to R11 (proven clusterbar).
__global__ __launch_bounds__(128, 1) void k_scan(
        const int* __restrict__ goal, const int* __restrict__ stem,
        const float* __restrict__ stem_emb,
        const s16* __restrict__ w_hi, const s16* __restrict__ w_lo,
        const float* __restrict__ b_hh, const float* __restrict__ gi_tok,
        unsigned* __restrict__ spk0, unsigned* __restrict__ spk1,
        unsigned* __restrict__ hsp, unsigned* bar) {
    __shared__ s16 wlds[96 * 512];   // 96 KB, viewed as [6][16][64][8]
    const int tid = threadIdx.x;
    const int wg = blockIdx.x;
    const int c = wg & 7;
    const int jt = wg >> 3;
    const int w = tid >> 6;
    const int l = tid & 63;
    const int ln = l & 15;
    const int kg = l >> 4;
    const int row0 = c * 32 + w * 16;   // this wave's 16 batch rows
    const int j = jt * 16 + ln;

    // one-time: stage weight slice into LDS, fragment-major.
    for (int i = tid; i < 6144; i += 128) {
        int lane = i & 63;
        int chunk = i >> 6;           // 0..95 = g2*16 + kcIdx
        int g2 = chunk >> 4;          // gate*2 + hl
        int kcIdx = chunk & 15;
        int gate = g2 >> 1, hl = g2 & 1;
        int lnn = lane & 15, kgg = lane >> 4;
        const s16* src = (hl ? w_lo : w_hi) +
                         ((size_t)(gate * H + jt * 16 + lnn)) * H + kcIdx * 32 + kgg * 8;
        *(s16x8*)(wlds + (size_t)i * 8) = *(const s16x8*)src;
    }
    // one-time: h0 (packed split) into spk0's fragment-major layout.
    // WG jt inits row b = c*32 + jt; thread tid covers cols tid*4 .. tid*4+4.
    {
        int b = c * 32 + jt;
        int blk = c * 2 + (jt >> 4);
        int lne = jt & 15;
        float4 v = ((const float4*)(stem_emb + (size_t)stem[b] * H))[tid];
        float xs[4] = {v.x, v.y, v.z, v.w};
        #pragma unroll
        for (int qq = 0; qq < 4; ++qq) {
            int col = tid * 4 + qq;
            int ku = col >> 1, s = col & 1;
            int ii = ku & 3, kgc = (ku >> 2) & 3, kc = ku >> 4;
            size_t slot = (size_t)blk * 8192 +
                          (size_t)(((kc * 4 + ii) * 64 + 16 * kgc + lne) * 2 + s);
            __hip_atomic_store(spk0 + slot, packsplit(xs[qq]),
                               __ATOMIC_RELAXED, __HIP_MEMORY_SCOPE_AGENT);
        }
    }
    // hprev in registers: exact h0 at this lane's (b, j) positions
    float hprev[4];
    #pragma unroll
    for (int q = 0; q < 4; ++q) {
        int b = row0 + kg * 4 + q;
        hprev[q] = stem_emb[(size_t)stem[b] * H + j];
    }
    // writer slot constants for column j: (ku,s,ii,kgc,kc); per q the
    // row-within-block is kg*4 + q. Used for BOTH spk and hsp (same layout).
    size_t wslot[4];
    {
        int ku = j >> 1, s = j & 1;
        int ii = ku & 3, kgc = (ku >> 2) & 3, kc = ku >> 4;
        size_t basef = (size_t)(c * 2 + w) * 8192 +
                       (size_t)(((kc * 4 + ii) * 64 + 16 * kgc) * 2 + s);
        #pragma unroll
        for (int q = 0; q < 4; ++q)
            wslot[q] = basef + (size_t)((kg * 4 + q) * 2);
    }
    clusterbar(bar, c, 1u, tid);

    const float bhr = b_hh[j], bhz = b_hh[H + j], bhn = b_hh[2 * H + j];

    for (int t = 0; t <= L; ++t) {
        unsigned* pin = (t & 1) ? spk1 : spk0;
        unsigned* pout = (t & 1) ? spk0 : spk1;
        unsigned* h_out = hsp + (size_t)(t < L ? t + 1 : 0) * SLOT;  // EOS -> slot 0

        // lane base in the fragment-major block: u64 index blk*4096 + l
        const u64* ap = (const u64*)pin + (size_t)(c * 2 + w) * 4096 + l;

        // token + gi prefetch (normal cached loads)
        int bq[4];
        float g0[4], g1[4], g2v[4];
        #pragma unroll
        for (int q = 0; q < 4; ++q) {
            bq[q] = row0 + kg * 4 + q;
            int v = (t < L) ? goal[(size_t)bq[q] * L + t] : EOS_TOK;
            const float* gi = gi_tok + (size_t)v * H3;
            g0[q] = gi[j];
            g1[q] = gi[H + j];
            g2v[q] = gi[2 * H + j];
        }

        // A-loads: instruction kcii reads 64 lanes x 8B contiguous (512 B)
        u64 av[64];
        #pragma unroll
        for (int kcii = 0; kcii < 64; ++kcii)
            av[kcii] = __hip_atomic_load(ap + (size_t)kcii * 64,
                                         __ATOMIC_RELAXED, __HIP_MEMORY_SCOPE_AGENT);

        f32x4v ar{}, az{}, an{};
        #pragma unroll
        for (int kcIdx = 0; kcIdx < 16; ++kcIdx) {
            s16x8 Ah, Al;
            #pragma unroll
            for (int i = 0; i < 4; ++i) {
                u64 wv = av[kcIdx * 4 + i];
                unsigned lo32 = (unsigned)wv, hi32 = (unsigned)(wv >> 32);
                Ah[2 * i]     = (s16)(lo32 & 0xffff);
                Al[2 * i]     = (s16)(lo32 >> 16);
                Ah[2 * i + 1] = (s16)(hi32 & 0xffff);
                Al[2 * i + 1] = (s16)(hi32 >> 16);
            }
            const s16* bb = wlds + ((size_t)(kcIdx * 64 + l)) * 8;
            s16x8 Rh = *(const s16x8*)(bb);
            s16x8 Rl = *(const s16x8*)(bb + 8192);
            s16x8 Zh = *(const s16x8*)(bb + 16384);
            s16x8 Zl = *(const s16x8*)(bb + 24576);
            s16x8 Nh = *(const s16x8*)(bb + 32768);
            s16x8 Nl = *(const s16x8*)(bb + 40960);
            ar = __builtin_amdgcn_mfma_f32_16x16x32_bf16(Ah, Rh, ar, 0, 0, 0);
            az = __builtin_amdgcn_mfma_f32_16x16x32_bf16(Ah, Zh, az, 0, 0, 0);
            an = __builtin_amdgcn_mfma_f32_16x16x32_bf16(Ah, Nh, an, 0, 0, 0);
            ar = __builtin_amdgcn_mfma_f32_16x16x32_bf16(Ah, Rl, ar, 0, 0, 0);
            az = __builtin_amdgcn_mfma_f32_16x16x32_bf16(Ah, Zl, az, 0, 0, 0);
            an = __builtin_amdgcn_mfma_f32_16x16x32_bf16(Ah, Nl, an, 0, 0, 0);
            ar = __builtin_amdgcn_mfma_f32_16x16x32_bf16(Al, Rh, ar, 0, 0, 0);
            az = __builtin_amdgcn_mfma_f32_16x16x32_bf16(Al, Zh, az, 0, 0, 0);
            an = __builtin_amdgcn_mfma_f32_16x16x32_bf16(Al, Nh, an, 0, 0, 0);
        }

        #pragma unroll
        for (int q = 0; q < 4; ++q) {
            float r = sigmoidf_(g0[q] + ar[q] + bhr);
            float z = sigmoidf_(g1[q] + az[q] + bhz);
            float x = g2v[q] + r * (an[q] + bhn);
            float e = __expf(-2.f * x);
            float nn = (1.f - e) / (1.f + e);         // tanh(x)
            float hn = (1.f - z) * nn + z * hprev[q];
            hprev[q] = hn;
            __builtin_nontemporal_store(packsplit(fmaxf(hn, 0.f)), h_out + wslot[q]);
            __hip_atomic_store(pout + wslot[q], packsplit(hn),
                               __ATOMIC_RELAXED, __HIP_MEMORY_SCOPE_AGENT);
        }

        if (t < L) clusterbar(bar, c, (unsigned)(t + 2), tid);
    }
}

// ---------------- fused MLP via MFMA (fragment-major packed states; packed v1 in LDS) ----------------
__global__ __launch_bounds__(256, 1) void k_mlp_mfma(
        const unsigned* __restrict__ statesp,
        const s16* __restrict__ w0h, const s16* __restrict__ w0l,
        const float* __restrict__ b0v,
        const s16* __restrict__ w1h, const s16* __restrict__ w1l,
        const float* __restrict__ b1v,
        const float* __restrict__ w2v, const float* __restrict__ b2v,
        float* __restrict__ out, int col0) {
    __shared__ unsigned v1s[64 * 512];   // 128 KB, packed-split v1
    __shared__ float red[4][64];
    const int tid = threadIdx.x;
    const int wid = tid >> 6;
    const int l = tid & 63;
    const int ln = l & 15;
    const int kg = l >> 4;
    const int r0 = blockIdx.x * 64;
    const int col = col0 + (r0 >> 8);
    const int b0 = r0 & 255;
    // fragment-major base for this block's slot (u64 units)
    const u64* slotb = (const u64*)statesp + (size_t)(r0 >> 8) * (SLOT / 2);
    const int blk0 = b0 >> 4;

    f32x4v acc[4][8];
    #pragma unroll
    for (int mf = 0; mf < 4; ++mf)
        #pragma unroll
        for (int nf = 0; nf < 8; ++nf) acc[mf][nf] = f32x4v{};

    // ---- GEMM1: v1 = relu(y @ w0.T + b0), y pre-packed-relu, fragment-major ----
    for (int kc = 0; kc < H; kc += 32) {
        const int kcIdx = kc >> 5;
        s16x8 Ah[4], Al[4];
        #pragma unroll
        for (int mf = 0; mf < 4; ++mf) {
            const u64* sb = slotb + (size_t)(blk0 + mf) * 4096 + l;
            #pragma unroll
            for (int i = 0; i < 4; ++i) {
                u64 wv = sb[(size_t)(kcIdx * 4 + i) * 64];
                unsigned lo32 = (unsigned)wv, hi32 = (unsigned)(wv >> 32);
                Ah[mf][2 * i]     = (s16)(lo32 & 0xffff);
                Al[mf][2 * i]     = (s16)(lo32 >> 16);
                Ah[mf][2 * i + 1] = (s16)(hi32 & 0xffff);
                Al[mf][2 * i + 1] = (s16)(hi32 >> 16);
            }
        }
        #pragma unroll
        for (int nf = 0; nf < 8; ++nf) {
            const int n = wid * 128 + nf * 16 + ln;
            s16x8 Bh = *(const s16x8*)(w0h + (size_t)n * H + kc + kg * 8);
            s16x8 Bl = *(const s16x8*)(w0l + (size_t)n * H + kc + kg * 8);
            #pragma unroll
            for (int mf = 0; mf < 4; ++mf) {
                acc[mf][nf] = __builtin_amdgcn_mfma_f32_16x16x32_bf16(Ah[mf], Bh, acc[mf][nf], 0, 0, 0);
                acc[mf][nf] = __builtin_amdgcn_mfma_f32_16x16x32_bf16(Ah[mf], Bl, acc[mf][nf], 0, 0, 0);
                acc[mf][nf] = __builtin_amdgcn_mfma_f32_16x16x32_bf16(Al[mf], Bh, acc[mf][nf], 0, 0, 0);
            }
        }
    }
    float bn[8];
    #pragma unroll
    for (int nf = 0; nf < 8; ++nf) bn[nf] = b0v[wid * 128 + nf * 16 + ln];
    #pragma unroll
    for (int mf = 0; mf < 4; ++mf)
        #pragma unroll
        for (int nf = 0; nf < 8; ++nf)
            #pragma unroll
            for (int q = 0; q < 4; ++q) {
                int m = mf * 16 + kg * 4 + q;
                int n = wid * 128 + nf * 16 + ln;
                v1s[m * 512 + (n ^ ((m & 7) << 2))] = packsplit(fmaxf(acc[mf][nf][q] + bn[nf], 0.f));
            }
    __syncthreads();

    // ---- GEMM2: v2 = relu(v1 @ w1.T + b1); lik = v2 . w2 ----
    #pragma unroll
    for (int mf = 0; mf < 4; ++mf)
        #pragma unroll
        for (int nf = 0; nf < 8; ++nf) acc[mf][nf] = f32x4v{};
    for (int kc = 0; kc < H; kc += 32) {
        s16x8 Ah[4], Al[4];
        #pragma unroll
        for (int mf = 0; mf < 4; ++mf) {
            const int rr = mf * 16 + ln;
            const int cx = (rr & 7) << 2;
            const int k0 = kc + kg * 8;
            uint4 p0 = *(const uint4*)(v1s + rr * 512 + (k0 ^ cx));
            uint4 p1 = *(const uint4*)(v1s + rr * 512 + ((k0 + 4) ^ cx));
            unsigned pv[8] = {p0.x, p0.y, p0.z, p0.w, p1.x, p1.y, p1.z, p1.w};
            #pragma unroll
            for (int i = 0; i < 8; ++i) {
                Ah[mf][i] = (s16)(pv[i] & 0xffff);
                Al[mf][i] = (s16)(pv[i] >> 16);
            }
        }
        #pragma unroll
        for (int nf = 0; nf < 8; ++nf) {
            const int n = wid * 128 + nf * 16 + ln;
            s16x8 Bh = *(const s16x8*)(w1h + (size_t)n * H + kc + kg * 8);
            s16x8 Bl = *(const s16x8*)(w1l + (size_t)n * H + kc + kg * 8);
            #pragma unroll
            for (int mf = 0; mf < 4; ++mf) {
                acc[mf][nf] = __builtin_amdgcn_mfma_f32_16x16x32_bf16(Ah[mf], Bh, acc[mf][nf], 0, 0, 0);
                acc[mf][nf] = __builtin_amdgcn_mfma_f32_16x16x32_bf16(Ah[mf], Bl, acc[mf][nf], 0, 0, 0);
                acc[mf][nf] = __builtin_amdgcn_mfma_f32_16x16x32_bf16(Al[mf], Bh, acc[mf][nf], 0, 0, 0);
            }
        }
    }
    float b1n[8], w2n[8];
    #pragma unroll
    for (int nf = 0; nf < 8; ++nf) {
        int n = wid * 128 + nf * 16 + ln;
        b1n[nf] = b1v[n];
        w2n[nf] = w2v[n];
    }
    float psum[4][4];
    #pragma unroll
    for (int mf = 0; mf < 4; ++mf)
        #pragma unroll
        for (int q = 0; q < 4; ++q) {
            float s = 0.f;
            #pragma unroll
            for (int nf = 0; nf < 8; ++nf)
                s += fmaxf(acc[mf][nf][q] + b1n[nf], 0.f) * w2n[nf];
            psum[mf][q] = s;
        }
    #pragma unroll
    for (int mf = 0; mf < 4; ++mf)
        #pragma unroll
        for (int q = 0; q < 4; ++q) {
            float s = psum[mf][q];
            #pragma unroll
            for (int msk = 1; msk < 16; msk <<= 1)
                s += __shfl_xor(s, msk, 64);
            psum[mf][q] = s;
        }
    if (ln == 0) {
        #pragma unroll
        for (int mf = 0; mf < 4; ++mf)
            #pragma unroll
            for (int q = 0; q < 4; ++q)
                red[wid][mf * 16 + kg * 4 + q] = psum[mf][q];
    }
    __syncthreads();
    if (tid < 64) {
        float s = b2v[0] + red[0][tid] + red[1][tid] + red[2][tid] + red[3][tid];
        out[(size_t)(b0 + tid) * OUTC + col] = s;
    }
}

extern "C" void kernel_launch(void* const* d_in, const int* in_sizes, int n_in,
                              void* d_out, int out_size, void* d_ws, size_t ws_size,
                              hipStream_t stream) {
    (void)in_sizes; (void)n_in; (void)out_size; (void)ws_size;
    const int* stem = (const int*)d_in[0];
    const int* goal = (const int*)d_in[1];
    const float* stem_emb = (const float*)d_in[2];
    const float* token_emb = (const float*)d_in[3];
    const float* w_ih = (const float*)d_in[4];
    const float* w_hh = (const float*)d_in[5];
    const float* b_ih = (const float*)d_in[6];
    const float* b_hh = (const float*)d_in[7];
    const float* w0 = (const float*)d_in[8];
    const float* b0 = (const float*)d_in[9];
    const float* w1 = (const float*)d_in[10];
    const float* b1 = (const float*)d_in[11];
    const float* w2 = (const float*)d_in[12];
    const float* b2 = (const float*)d_in[13];
    float* out = (float*)d_out;

    char* p = (char*)d_ws;
    float* gi_tok = (float*)p;      p += (size_t)TOKV * H3 * 4;
    s16* whh_h = (s16*)p;           p += (size_t)H3 * H * 2;
    s16* whh_l = (s16*)p;           p += (size_t)H3 * H * 2;
    s16* w0h = (s16*)p;             p += (size_t)H * H * 2;
    s16* w0l = (s16*)p;             p += (size_t)H * H * 2;
    s16* w1h = (s16*)p;             p += (size_t)H * H * 2;
    s16* w1l = (s16*)p;             p += (size_t)H * H * 2;
    unsigned* spk0 = (unsigned*)p;  p += SLOT * 4;
    unsigned* spk1 = (unsigned*)p;  p += SLOT * 4;
    unsigned* bar = (unsigned*)p;   p += 4096;
    unsigned* hsp = (unsigned*)p;   // 257 packed slots: [0]=EOS, [1..256]=steps

    hipMemsetAsync(bar, 0, 4096, stream);

    // prep
    k_split<<<768, 256, 0, stream>>>(w_hh, whh_h, whh_l, H3 * H / 4);
    k_split<<<256, 256, 0, stream>>>(w0, w0h, w0l, H * H / 4);
    k_split<<<256, 256, 0, stream>>>(w1, w1h, w1l, H * H / 4);
    k_gi_tok<<<128, 256, 0, stream>>>(token_emb, w_ih, b_ih, gi_tok);

    // persistent clustered scan (h0 init + 256 GRU steps + EOS step).
    // Cooperative launch preferred; on ANY failure fall back to a plain
    // launch (1 WG/CU resources + idle GPU => co-resident in practice).
    {
        const int* goal_a = goal;
        const int* stem_a = stem;
        const float* stem_emb_a = stem_emb;
        const s16* whh_h_a = whh_h;
        const s16* whh_l_a = whh_l;
        const float* b_hh_a = b_hh;
        const float* gi_tok_a = gi_tok;
        unsigned* spk0_a = spk0;
        unsigned* spk1_a = spk1;
        unsigned* hsp_a = hsp;
        unsigned* bar_a = bar;
        void* kargs[] = {(void*)&goal_a, (void*)&stem_a, (void*)&stem_emb_a,
                         (void*)&whh_h_a, (void*)&whh_l_a, (void*)&b_hh_a,
                         (void*)&gi_tok_a, (void*)&spk0_a, (void*)&spk1_a,
                         (void*)&hsp_a, (void*)&bar_a};
        hipError_t ce = hipLaunchCooperativeKernel((void*)k_scan, dim3(256),
                                                   dim3(128), kargs, 0, stream);
        if (ce != hipSuccess) {
            k_scan<<<256, 128, 0, stream>>>(goal, stem, stem_emb, whh_h, whh_l,
                                            b_hh, gi_tok, spk0, spk1, hsp, bar);
        }
    }

    // MLP: cols 1..256 from hsp slots 1..256, col 0 (EOS) from hsp slot 0
    k_mlp_mfma<<<1024, 256, 0, stream>>>(hsp + SLOT, w0h, w0l, b0,
                                         w1h, w1l, b1, w2, b2, out, 1);
    k_mlp_mfma<<<4, 256, 0, stream>>>(hsp, w0h, w0l, b0,
                                      w1h, w1l, b1, w2, b2, out, 0);
}

// Round 14
// 1658.012 us; speedup vs baseline: 1.5125x; 1.0315x over previous
//
#include <hip/hip_runtime.h>
#include <math.h>

#define B 256
#define L 256
#define H 512
#define H3 1536
#define TOKV 128
#define EOS_TOK 1
#define OUTC 257
#define SLOT ((size_t)B * H)   // u32 elements per h-state slot

typedef short s16;
typedef s16 s16x8 __attribute__((ext_vector_type(8)));
typedef s16 s16x4 __attribute__((ext_vector_type(4)));
typedef float f32x4v __attribute__((ext_vector_type(4)));
typedef unsigned long long u64;

__device__ __forceinline__ float sigmoidf_(float x) {
    return 1.0f / (1.0f + __expf(-x));
}

// fp32 -> bf16 bit pattern, round-to-nearest-even (same as (__bf16) cast)
__device__ __forceinline__ s16 f2bf(float x) {
    unsigned u = __builtin_bit_cast(unsigned, x);
    u += 0x7fffu + ((u >> 16) & 1u);
    return (s16)(u >> 16);
}
__device__ __forceinline__ float bf2f(s16 h) {
    return __builtin_bit_cast(float, ((unsigned)(unsigned short)h) << 16);
}
// pack hi(low16)|lo(high16) of a float's 2-term bf16 split
__device__ __forceinline__ unsigned packsplit(float x) {
    s16 hh = f2bf(x);
    s16 ll = f2bf(x - bf2f(hh));
    return (unsigned)(unsigned short)hh | ((unsigned)(unsigned short)ll << 16);
}
// relu on a packed split value: h < 0  <=>  sign bit of hi (bit 15) set
__device__ __forceinline__ unsigned relu_pk(unsigned pv) {
    int m = ((int)(pv << 16)) >> 31;      // all-ones if hi negative
    return pv & ~(unsigned)m;
}

// ---------------- per-cluster barrier (monotonic, relaxed + compiler fences) ----------------
// Proven in R6/R7/R9/R11/R13. Counters zeroed per launch -> replay-deterministic.
__device__ __forceinline__ void clusterbar(unsigned* bar, int c, unsigned n, int tid) {
    __syncthreads();
    if (tid == 0) {
        const unsigned tgt = 32u * n;
        unsigned* ctr = bar + c * 32;
        asm volatile("" ::: "memory");
        __hip_atomic_fetch_add(ctr, 1u, __ATOMIC_RELAXED, __HIP_MEMORY_SCOPE_AGENT);
        while (__hip_atomic_load(ctr, __ATOMIC_RELAXED, __HIP_MEMORY_SCOPE_AGENT) < tgt)
            __builtin_amdgcn_s_sleep(1);
        asm volatile("" ::: "memory");
    }
    __syncthreads();
}

// ---------------- prep: elementwise split of a fp32 weight array ----------------
__global__ __launch_bounds__(256) void k_split(const float* __restrict__ src,
                                               s16* __restrict__ hi,
                                               s16* __restrict__ lo, int n4) {
    int i = blockIdx.x * 256 + threadIdx.x;
    if (i >= n4) return;
    float4 x = ((const float4*)src)[i];
    float xs[4] = {x.x, x.y, x.z, x.w};
    s16x4 h, l;
    #pragma unroll
    for (int q = 0; q < 4; ++q) {
        s16 hh = f2bf(xs[q]);
        h[q] = hh;
        l[q] = f2bf(xs[q] - bf2f(hh));
    }
    *(s16x4*)(hi + (size_t)i * 4) = h;
    *(s16x4*)(lo + (size_t)i * 4) = l;
}

// ---------------- prep: gi_tok[v][j] = relu(token_emb[v]) . w_ih[j] + b_ih[j] (fp32) ----------------
__global__ __launch_bounds__(256) void k_gi_tok(
        const float* __restrict__ token_emb, const float* __restrict__ w_ih,
        const float* __restrict__ b_ih, float* __restrict__ gi_out) {
    __shared__ float wlds[96][132];
    __shared__ float elds[16][132];
    const int vi = blockIdx.x >> 4;
    const int ji = blockIdx.x & 15;
    const int v0 = vi << 4, j0 = ji * 96;
    const int tid = threadIdx.x;
    const int vl = tid & 7;
    const int jl = tid >> 3;
    float acc[2][3] = {{0.f, 0.f, 0.f}, {0.f, 0.f, 0.f}};
    for (int ck = 0; ck < 4; ++ck) {
        const int c0 = ck << 7;
        __syncthreads();
        for (int i = tid; i < 96 * 32; i += 256) {
            int row = i >> 5, c4 = i & 31;
            *(float4*)&wlds[row][c4 << 2] =
                *(const float4*)(w_ih + (size_t)(j0 + row) * H + c0 + (c4 << 2));
        }
        for (int i = tid; i < 16 * 32; i += 256) {
            int row = i >> 5, c4 = i & 31;
            float4 e = *(const float4*)(token_emb + (size_t)(v0 + row) * H + c0 + (c4 << 2));
            e.x = fmaxf(e.x, 0.f); e.y = fmaxf(e.y, 0.f);
            e.z = fmaxf(e.z, 0.f); e.w = fmaxf(e.w, 0.f);
            *(float4*)&elds[row][c4 << 2] = e;
        }
        __syncthreads();
        #pragma unroll 8
        for (int c = 0; c < 128; c += 4) {
            float4 wa = *(const float4*)&wlds[jl][c];
            float4 wb = *(const float4*)&wlds[32 + jl][c];
            float4 wc = *(const float4*)&wlds[64 + jl][c];
            float4 ea = *(const float4*)&elds[vl][c];
            float4 eb = *(const float4*)&elds[vl + 8][c];
            acc[0][0] += ea.x*wa.x + ea.y*wa.y + ea.z*wa.z + ea.w*wa.w;
            acc[0][1] += ea.x*wb.x + ea.y*wb.y + ea.z*wb.z + ea.w*wb.w;
            acc[0][2] += ea.x*wc.x + ea.y*wc.y + ea.z*wc.z + ea.w*wc.w;
            acc[1][0] += eb.x*wa.x + eb.y*wa.y + eb.z*wa.z + eb.w*wa.w;
            acc[1][1] += eb.x*wb.x + eb.y*wb.y + eb.z*wb.z + eb.w*wb.w;
            acc[1][2] += eb.x*wc.x + eb.y*wc.y + eb.z*wc.z + eb.w*wc.w;
        }
    }
    #pragma unroll
    for (int p = 0; p < 2; ++p) {
        int v = v0 + vl + (p << 3);
        #pragma unroll
        for (int s = 0; s < 3; ++s) {
            int j = j0 + (s << 5) + jl;
            gi_out[(size_t)v * H3 + j] = acc[p][s] + b_ih[j];
        }
    }
}

// ---------------- persistent GRU scan, clustered (256 WGs x 128 thr) ----------------
// UNIFIED write-once state buffer hsp: 258 slots (tau: 0=h0, 1..256=steps,
// 257=EOS), fragment-major per 16-row block (blk = c*2+w): u64 f =
// (kc*4+ii)*64 + kgc*16 + row holds (row, cols kc*32+kgc*8+2*ii+{0,1}) packed
// u32 (bf16hi|lo<<16). Step t reads slot t (sc1 u64, 512B-contiguous per
// instruction), writes slot t+1 via wave-local LDS staging -> 2 coalesced
// sc1 u64 stores per lane (256B runs). Sync identical to R13 (proven).
__global__ __launch_bounds__(128, 1) void k_scan(
        const int* __restrict__ goal, const int* __restrict__ stem,
        const float* __restrict__ stem_emb,
        const s16* __restrict__ w_hi, const s16* __restrict__ w_lo,
        const float* __restrict__ b_hh, const float* __restrict__ gi_tok,
        unsigned* __restrict__ hsp, unsigned* bar) {
    __shared__ s16 wlds[96 * 512];       // 96 KB, viewed as [6][16][64][8]
    __shared__ unsigned stage[2][512];   // 2 KB per wave, fragment-major staging
    const int tid = threadIdx.x;
    const int wg = blockIdx.x;
    const int c = wg & 7;
    const int jt = wg >> 3;
    const int w = tid >> 6;
    const int l = tid & 63;
    const int ln = l & 15;
    const int kg = l >> 4;
    const int row0 = c * 32 + w * 16;   // this wave's 16 batch rows
    const int j = jt * 16 + ln;

    // one-time: stage weight slice into LDS, fragment-major.
    for (int i = tid; i < 6144; i += 128) {
        int lane = i & 63;
        int chunk = i >> 6;           // 0..95 = g2*16 + kcIdx
        int g2 = chunk >> 4;          // gate*2 + hl
        int kcIdx = chunk & 15;
        int gate = g2 >> 1, hl = g2 & 1;
        int lnn = lane & 15, kgg = lane >> 4;
        const s16* src = (hl ? w_lo : w_hi) +
                         ((size_t)(gate * H + jt * 16 + lnn)) * H + kcIdx * 32 + kgg * 8;
        *(s16x8*)(wlds + (size_t)i * 8) = *(const s16x8*)src;
    }
    // one-time: h0 (packed split) into hsp slot 0, fragment-major.
    // WG jt inits row b = c*32 + jt; thread tid covers cols tid*4 .. tid*4+4.
    {
        int b = c * 32 + jt;
        int blk = c * 2 + (jt >> 4);
        int lne = jt & 15;
        float4 v = ((const float4*)(stem_emb + (size_t)stem[b] * H))[tid];
        float xs[4] = {v.x, v.y, v.z, v.w};
        #pragma unroll
        for (int qq = 0; qq < 4; ++qq) {
            int col = tid * 4 + qq;
            int ku = col >> 1, s = col & 1;
            int ii = ku & 3, kgc = (ku >> 2) & 3, kc = ku >> 4;
            size_t slot = (size_t)blk * 8192 +
                          (size_t)(((kc * 4 + ii) * 64 + 16 * kgc + lne) * 2 + s);
            __hip_atomic_store(hsp + slot, packsplit(xs[qq]),
                               __ATOMIC_RELAXED, __HIP_MEMORY_SCOPE_AGENT);
        }
    }
    // hprev in registers: exact h0 at this lane's (b, j) positions
    float hprev[4];
    #pragma unroll
    for (int q = 0; q < 4; ++q) {
        int b = row0 + kg * 4 + q;
        hprev[q] = stem_emb[(size_t)stem[b] * H + j];
    }
    clusterbar(bar, c, 1u, tid);

    const float bhr = b_hh[j], bhz = b_hh[H + j], bhn = b_hh[2 * H + j];
    // epilogue constants
    const int ii2g = ((ln >> 1) & 3) * 2 + (ln >> 3);
    const int sbit = ln & 1;
    const size_t wavebase = (size_t)(c * 2 + w) * 4096 +
                            (size_t)(jt >> 1) * 256 + (size_t)(jt & 1) * 32 + (l & 31);

    for (int t = 0; t <= L; ++t) {
        const int tau_out = (t < L) ? t + 1 : 257;
        const u64* ap = (const u64*)hsp + (size_t)t * (SLOT / 2) +
                        (size_t)(c * 2 + w) * 4096 + l;

        // token + gi prefetch (normal cached loads)
        int bq[4];
        float g0[4], g1[4], g2v[4];
        #pragma unroll
        for (int q = 0; q < 4; ++q) {
            bq[q] = row0 + kg * 4 + q;
            int v = (t < L) ? goal[(size_t)bq[q] * L + t] : EOS_TOK;
            const float* gi = gi_tok + (size_t)v * H3;
            g0[q] = gi[j];
            g1[q] = gi[H + j];
            g2v[q] = gi[2 * H + j];
        }

        // A-loads: instruction kcii reads 64 lanes x 8B contiguous (512 B)
        u64 av[64];
        #pragma unroll
        for (int kcii = 0; kcii < 64; ++kcii)
            av[kcii] = __hip_atomic_load(ap + (size_t)kcii * 64,
                                         __ATOMIC_RELAXED, __HIP_MEMORY_SCOPE_AGENT);

        f32x4v ar{}, az{}, an{};
        #pragma unroll
        for (int kcIdx = 0; kcIdx < 16; ++kcIdx) {
            s16x8 Ah, Al;
            #pragma unroll
            for (int i = 0; i < 4; ++i) {
                u64 wv = av[kcIdx * 4 + i];
                unsigned lo32 = (unsigned)wv, hi32 = (unsigned)(wv >> 32);
                Ah[2 * i]     = (s16)(lo32 & 0xffff);
                Al[2 * i]     = (s16)(lo32 >> 16);
                Ah[2 * i + 1] = (s16)(hi32 & 0xffff);
                Al[2 * i + 1] = (s16)(hi32 >> 16);
            }
            const s16* bb = wlds + ((size_t)(kcIdx * 64 + l)) * 8;
            s16x8 Rh = *(const s16x8*)(bb);
            s16x8 Rl = *(const s16x8*)(bb + 8192);
            s16x8 Zh = *(const s16x8*)(bb + 16384);
            s16x8 Zl = *(const s16x8*)(bb + 24576);
            s16x8 Nh = *(const s16x8*)(bb + 32768);
            s16x8 Nl = *(const s16x8*)(bb + 40960);
            ar = __builtin_amdgcn_mfma_f32_16x16x32_bf16(Ah, Rh, ar, 0, 0, 0);
            az = __builtin_amdgcn_mfma_f32_16x16x32_bf16(Ah, Zh, az, 0, 0, 0);
            an = __builtin_amdgcn_mfma_f32_16x16x32_bf16(Ah, Nh, an, 0, 0, 0);
            ar = __builtin_amdgcn_mfma_f32_16x16x32_bf16(Ah, Rl, ar, 0, 0, 0);
            az = __builtin_amdgcn_mfma_f32_16x16x32_bf16(Ah, Zl, az, 0, 0, 0);
            an = __builtin_amdgcn_mfma_f32_16x16x32_bf16(Ah, Nl, an, 0, 0, 0);
            ar = __builtin_amdgcn_mfma_f32_16x16x32_bf16(Al, Rh, ar, 0, 0, 0);
            az = __builtin_amdgcn_mfma_f32_16x16x32_bf16(Al, Zh, az, 0, 0, 0);
            an = __builtin_amdgcn_mfma_f32_16x16x32_bf16(Al, Nh, an, 0, 0, 0);
        }

        // epilogue: compute, pack, stage in LDS (wave-local), store coalesced
        unsigned pv[4];
        #pragma unroll
        for (int q = 0; q < 4; ++q) {
            float r = sigmoidf_(g0[q] + ar[q] + bhr);
            float z = sigmoidf_(g1[q] + az[q] + bhz);
            float x = g2v[q] + r * (an[q] + bhn);
            float e = __expf(-2.f * x);
            float nn = (1.f - e) / (1.f + e);         // tanh(x)
            float hn = (1.f - z) * nn + z * hprev[q];
            hprev[q] = hn;
            pv[q] = packsplit(hn);
        }
        {
            unsigned* st = stage[w];
            #pragma unroll
            for (int q = 0; q < 4; ++q)
                st[ii2g * 32 + (kg * 4 + q) * 2 + sbit] = pv[q];
            const u64* stu = (const u64*)stage[w];
            u64* outp = (u64*)hsp + (size_t)tau_out * (SLOT / 2) + wavebase;
            #pragma unroll
            for (int k = 0; k < 2; ++k) {
                int iis = k * 2 + (l >> 5);
                __hip_atomic_store(outp + (size_t)iis * 64, stu[iis * 32 + (l & 31)],
                                   __ATOMIC_RELAXED, __HIP_MEMORY_SCOPE_AGENT);
            }
        }

        if (t < L) clusterbar(bar, c, (unsigned)(t + 2), tid);
    }
}

// ---------------- fused MLP via MFMA (fragment-major packed states; relu on unpack) ----------------
__global__ __launch_bounds__(256, 1) void k_mlp_mfma(
        const unsigned* __restrict__ statesp,
        const s16* __restrict__ w0h, const s16* __restrict__ w0l,
        const float* __restrict__ b0v,
        const s16* __restrict__ w1h, const s16* __restrict__ w1l,
        const float* __restrict__ b1v,
        const float* __restrict__ w2v, const float* __restrict__ b2v,
        float* __restrict__ out, int col0) {
    __shared__ unsigned v1s[64 * 512];   // 128 KB, packed-split v1
    __shared__ float red[4][64];
    const int tid = threadIdx.x;
    const int wid = tid >> 6;
    const int l = tid & 63;
    const int ln = l & 15;
    const int kg = l >> 4;
    const int r0 = blockIdx.x * 64;
    const int col = col0 + (r0 >> 8);
    const int b0 = r0 & 255;
    // fragment-major base for this block's slot (u64 units)
    const u64* slotb = (const u64*)statesp + (size_t)(r0 >> 8) * (SLOT / 2);
    const int blk0 = b0 >> 4;

    f32x4v acc[4][8];
    #pragma unroll
    for (int mf = 0; mf < 4; ++mf)
        #pragma unroll
        for (int nf = 0; nf < 8; ++nf) acc[mf][nf] = f32x4v{};

    // ---- GEMM1: v1 = relu(relu(h) @ w0.T + b0), fragment-major packed h ----
    for (int kc = 0; kc < H; kc += 32) {
        const int kcIdx = kc >> 5;
        s16x8 Ah[4], Al[4];
        #pragma unroll
        for (int mf = 0; mf < 4; ++mf) {
            const u64* sb = slotb + (size_t)(blk0 + mf) * 4096 + l;
            #pragma unroll
            for (int i = 0; i < 4; ++i) {
                u64 wv = sb[(size_t)(kcIdx * 4 + i) * 64];
                unsigned lo32 = relu_pk((unsigned)wv);
                unsigned hi32 = relu_pk((unsigned)(wv >> 32));
                Ah[mf][2 * i]     = (s16)(lo32 & 0xffff);
                Al[mf][2 * i]     = (s16)(lo32 >> 16);
                Ah[mf][2 * i + 1] = (s16)(hi32 & 0xffff);
                Al[mf][2 * i + 1] = (s16)(hi32 >> 16);
            }
        }
        #pragma unroll
        for (int nf = 0; nf < 8; ++nf) {
            const int n = wid * 128 + nf * 16 + ln;
            s16x8 Bh = *(const s16x8*)(w0h + (size_t)n * H + kc + kg * 8);
            s16x8 Bl = *(const s16x8*)(w0l + (size_t)n * H + kc + kg * 8);
            #pragma unroll
            for (int mf = 0; mf < 4; ++mf) {
                acc[mf][nf] = __builtin_amdgcn_mfma_f32_16x16x32_bf16(Ah[mf], Bh, acc[mf][nf], 0, 0, 0);
                acc[mf][nf] = __builtin_amdgcn_mfma_f32_16x16x32_bf16(Ah[mf], Bl, acc[mf][nf], 0, 0, 0);
                acc[mf][nf] = __builtin_amdgcn_mfma_f32_16x16x32_bf16(Al[mf], Bh, acc[mf][nf], 0, 0, 0);
            }
        }
    }
    float bn[8];
    #pragma unroll
    for (int nf = 0; nf < 8; ++nf) bn[nf] = b0v[wid * 128 + nf * 16 + ln];
    #pragma unroll
    for (int mf = 0; mf < 4; ++mf)
        #pragma unroll
        for (int nf = 0; nf < 8; ++nf)
            #pragma unroll
            for (int q = 0; q < 4; ++q) {
                int m = mf * 16 + kg * 4 + q;
                int n = wid * 128 + nf * 16 + ln;
                v1s[m * 512 + (n ^ ((m & 7) << 2))] = packsplit(fmaxf(acc[mf][nf][q] + bn[nf], 0.f));
            }
    __syncthreads();

    // ---- GEMM2: v2 = relu(v1 @ w1.T + b1); lik = v2 . w2 ----
    #pragma unroll
    for (int mf = 0; mf < 4; ++mf)
        #pragma unroll
        for (int nf = 0; nf < 8; ++nf) acc[mf][nf] = f32x4v{};
    for (int kc = 0; kc < H; kc += 32) {
        s16x8 Ah[4], Al[4];
        #pragma unroll
        for (int mf = 0; mf < 4; ++mf) {
            const int rr = mf * 16 + ln;
            const int cx = (rr & 7) << 2;
            const int k0 = kc + kg * 8;
            uint4 p0 = *(const uint4*)(v1s + rr * 512 + (k0 ^ cx));
            uint4 p1 = *(const uint4*)(v1s + rr * 512 + ((k0 + 4) ^ cx));
            unsigned pv[8] = {p0.x, p0.y, p0.z, p0.w, p1.x, p1.y, p1.z, p1.w};
            #pragma unroll
            for (int i = 0; i < 8; ++i) {
                Ah[mf][i] = (s16)(pv[i] & 0xffff);
                Al[mf][i] = (s16)(pv[i] >> 16);
            }
        }
        #pragma unroll
        for (int nf = 0; nf < 8; ++nf) {
            const int n = wid * 128 + nf * 16 + ln;
            s16x8 Bh = *(const s16x8*)(w1h + (size_t)n * H + kc + kg * 8);
            s16x8 Bl = *(const s16x8*)(w1l + (size_t)n * H + kc + kg * 8);
            #pragma unroll
            for (int mf = 0; mf < 4; ++mf) {
                acc[mf][nf] = __builtin_amdgcn_mfma_f32_16x16x32_bf16(Ah[mf], Bh, acc[mf][nf], 0, 0, 0);
                acc[mf][nf] = __builtin_amdgcn_mfma_f32_16x16x32_bf16(Ah[mf], Bl, acc[mf][nf], 0, 0, 0);
                acc[mf][nf] = __builtin_amdgcn_mfma_f32_16x16x32_bf16(Al[mf], Bh, acc[mf][nf], 0, 0, 0);
            }
        }
    }
    float b1n[8], w2n[8];
    #pragma unroll
    for (int nf = 0; nf < 8; ++nf) {
        int n = wid * 128 + nf * 16 + ln;
        b1n[nf] = b1v[n];
        w2n[nf] = w2v[n];
    }
    float psum[4][4];
    #pragma unroll
    for (int mf = 0; mf < 4; ++mf)
        #pragma unroll
        for (int q = 0; q < 4; ++q) {
            float s = 0.f;
            #pragma unroll
            for (int nf = 0; nf < 8; ++nf)
                s += fmaxf(acc[mf][nf][q] + b1n[nf], 0.f) * w2n[nf];
            psum[mf][q] = s;
        }
    #pragma unroll
    for (int mf = 0; mf < 4; ++mf)
        #pragma unroll
        for (int q = 0; q < 4; ++q) {
            float s = psum[mf][q];
            #pragma unroll
            for (int msk = 1; msk < 16; msk <<= 1)
                s += __shfl_xor(s, msk, 64);
            psum[mf][q] = s;
        }
    if (ln == 0) {
        #pragma unroll
        for (int mf = 0; mf < 4; ++mf)
            #pragma unroll
            for (int q = 0; q < 4; ++q)
                red[wid][mf * 16 + kg * 4 + q] = psum[mf][q];
    }
    __syncthreads();
    if (tid < 64) {
        float s = b2v[0] + red[0][tid] + red[1][tid] + red[2][tid] + red[3][tid];
        out[(size_t)(b0 + tid) * OUTC + col] = s;
    }
}

extern "C" void kernel_launch(void* const* d_in, const int* in_sizes, int n_in,
                              void* d_out, int out_size, void* d_ws, size_t ws_size,
                              hipStream_t stream) {
    (void)in_sizes; (void)n_in; (void)out_size; (void)ws_size;
    const int* stem = (const int*)d_in[0];
    const int* goal = (const int*)d_in[1];
    const float* stem_emb = (const float*)d_in[2];
    const float* token_emb = (const float*)d_in[3];
    const float* w_ih = (const float*)d_in[4];
    const float* w_hh = (const float*)d_in[5];
    const float* b_ih = (const float*)d_in[6];
    const float* b_hh = (const float*)d_in[7];
    const float* w0 = (const float*)d_in[8];
    const float* b0 = (const float*)d_in[9];
    const float* w1 = (const float*)d_in[10];
    const float* b1 = (const float*)d_in[11];
    const float* w2 = (const float*)d_in[12];
    const float* b2 = (const float*)d_in[13];
    float* out = (float*)d_out;

    char* p = (char*)d_ws;
    float* gi_tok = (float*)p;      p += (size_t)TOKV * H3 * 4;
    s16* whh_h = (s16*)p;           p += (size_t)H3 * H * 2;
    s16* whh_l = (s16*)p;           p += (size_t)H3 * H * 2;
    s16* w0h = (s16*)p;             p += (size_t)H * H * 2;
    s16* w0l = (s16*)p;             p += (size_t)H * H * 2;
    s16* w1h = (s16*)p;             p += (size_t)H * H * 2;
    s16* w1l = (s16*)p;             p += (size_t)H * H * 2;
    unsigned* bar = (unsigned*)p;   p += 4096;
    unsigned* hsp = (unsigned*)p;   // 258 packed slots: 0=h0, 1..256=steps, 257=EOS

    hipMemsetAsync(bar, 0, 4096, stream);

    // prep
    k_split<<<768, 256, 0, stream>>>(w_hh, whh_h, whh_l, H3 * H / 4);
    k_split<<<256, 256, 0, stream>>>(w0, w0h, w0l, H * H / 4);
    k_split<<<256, 256, 0, stream>>>(w1, w1h, w1l, H * H / 4);
    k_gi_tok<<<128, 256, 0, stream>>>(token_emb, w_ih, b_ih, gi_tok);

    // persistent clustered scan (h0 init + 256 GRU steps + EOS step).
    // Cooperative launch preferred; on ANY failure fall back to a plain
    // launch (1 WG/CU resources + idle GPU => co-resident in practice).
    {
        const int* goal_a = goal;
        const int* stem_a = stem;
        const float* stem_emb_a = stem_emb;
        const s16* whh_h_a = whh_h;
        const s16* whh_l_a = whh_l;
        const float* b_hh_a = b_hh;
        const float* gi_tok_a = gi_tok;
        unsigned* hsp_a = hsp;
        unsigned* bar_a = bar;
        void* kargs[] = {(void*)&goal_a, (void*)&stem_a, (void*)&stem_emb_a,
                         (void*)&whh_h_a, (void*)&whh_l_a, (void*)&b_hh_a,
                         (void*)&gi_tok_a, (void*)&hsp_a, (void*)&bar_a};
        hipError_t ce = hipLaunchCooperativeKernel((void*)k_scan, dim3(256),
                                                   dim3(128), kargs, 0, stream);
        if (ce != hipSuccess) {
            k_scan<<<256, 128, 0, stream>>>(goal, stem, stem_emb, whh_h, whh_l,
                                            b_hh, gi_tok, hsp, bar);
        }
    }

    // MLP: cols 1..256 from slots 1..256, col 0 (EOS) from slot 257
    k_mlp_mfma<<<1024, 256, 0, stream>>>(hsp + SLOT, w0h, w0l, b0,
                                         w1h, w1l, b1, w2, b2, out, 1);
    k_mlp_mfma<<<4, 256, 0, stream>>>(hsp + (size_t)257 * SLOT, w0h, w0l, b0,
                                      w1h, w1l, b1, w2, b2, out, 0);
}

// Round 17
// 1643.764 us; speedup vs baseline: 1.5256x; 1.0087x over previous
//
#include <hip/hip_runtime.h>
#include <math.h>

#define B 256
#define L 256
#define H 512
#define H3 1536
#define TOKV 128
#define EOS_TOK 1
#define OUTC 257
#define SLOT ((size_t)B * H)   // u32 elements per h-state slot

typedef short s16;
typedef s16 s16x8 __attribute__((ext_vector_type(8)));
typedef s16 s16x4 __attribute__((ext_vector_type(4)));
typedef float f32x4v __attribute__((ext_vector_type(4)));
typedef unsigned long long u64;

__device__ __forceinline__ float sigmoidf_(float x) {
    return 1.0f / (1.0f + __expf(-x));
}

// fp32 -> bf16 bit pattern, round-to-nearest-even (same as (__bf16) cast)
__device__ __forceinline__ s16 f2bf(float x) {
    unsigned u = __builtin_bit_cast(unsigned, x);
    u += 0x7fffu + ((u >> 16) & 1u);
    return (s16)(u >> 16);
}
__device__ __forceinline__ float bf2f(s16 h) {
    return __builtin_bit_cast(float, ((unsigned)(unsigned short)h) << 16);
}
// pack hi(low16)|lo(high16) of a float's 2-term bf16 split
__device__ __forceinline__ unsigned packsplit(float x) {
    s16 hh = f2bf(x);
    s16 ll = f2bf(x - bf2f(hh));
    return (unsigned)(unsigned short)hh | ((unsigned)(unsigned short)ll << 16);
}
// relu on a packed split value: h < 0  <=>  sign bit of hi (low 16) set
__device__ __forceinline__ unsigned relu_pk(unsigned pv) {
    int m = ((int)(pv << 16)) >> 31;      // all-ones if hi negative
    return pv & ~(unsigned)m;
}

// ---------------- per-cluster barrier (monotonic RMW; PROVEN R6/7/9/11/13/14) ----------------
__device__ __forceinline__ void clusterbar(unsigned* bar, int c, unsigned n, int tid) {
    __syncthreads();
    if (tid == 0) {
        const unsigned tgt = 32u * n;
        unsigned* ctr = bar + c * 32;
        asm volatile("" ::: "memory");
        __hip_atomic_fetch_add(ctr, 1u, __ATOMIC_RELAXED, __HIP_MEMORY_SCOPE_AGENT);
        while (__hip_atomic_load(ctr, __ATOMIC_RELAXED, __HIP_MEMORY_SCOPE_AGENT) < tgt)
            __builtin_amdgcn_s_sleep(1);
        asm volatile("" ::: "memory");
    }
    __syncthreads();
}

// ---------------- prep: split w_hh, w0, w1 in ONE launch ----------------
#define N4_WHH (H3 * H / 4)
#define N4_W   (H * H / 4)
__global__ __launch_bounds__(256) void k_split_all(
        const float* __restrict__ whh, s16* __restrict__ whh_h, s16* __restrict__ whh_l,
        const float* __restrict__ w0, s16* __restrict__ w0h, s16* __restrict__ w0l,
        const float* __restrict__ w1, s16* __restrict__ w1h, s16* __restrict__ w1l) {
    int i = blockIdx.x * 256 + threadIdx.x;
    const float* src;
    s16 *hi, *lo;
    int idx;
    if (i < N4_WHH) {
        src = whh; hi = whh_h; lo = whh_l; idx = i;
    } else if (i < N4_WHH + N4_W) {
        src = w0; hi = w0h; lo = w0l; idx = i - N4_WHH;
    } else if (i < N4_WHH + 2 * N4_W) {
        src = w1; hi = w1h; lo = w1l; idx = i - N4_WHH - N4_W;
    } else {
        return;
    }
    float4 x = ((const float4*)src)[idx];
    float xs[4] = {x.x, x.y, x.z, x.w};
    s16x4 h, l;
    #pragma unroll
    for (int q = 0; q < 4; ++q) {
        s16 hh = f2bf(xs[q]);
        h[q] = hh;
        l[q] = f2bf(xs[q] - bf2f(hh));
    }
    *(s16x4*)(hi + (size_t)idx * 4) = h;
    *(s16x4*)(lo + (size_t)idx * 4) = l;
}

// ---------------- prep: gi_tok[v][j] = relu(token_emb[v]) . w_ih[j] + b_ih[j] (fp32) ----------------
__global__ __launch_bounds__(256) void k_gi_tok(
        const float* __restrict__ token_emb, const float* __restrict__ w_ih,
        const float* __restrict__ b_ih, float* __restrict__ gi_out) {
    __shared__ float wlds[96][132];
    __shared__ float elds[16][132];
    const int vi = blockIdx.x >> 4;
    const int ji = blockIdx.x & 15;
    const int v0 = vi << 4, j0 = ji * 96;
    const int tid = threadIdx.x;
    const int vl = tid & 7;
    const int jl = tid >> 3;
    float acc[2][3] = {{0.f, 0.f, 0.f}, {0.f, 0.f, 0.f}};
    for (int ck = 0; ck < 4; ++ck) {
        const int c0 = ck << 7;
        __syncthreads();
        for (int i = tid; i < 96 * 32; i += 256) {
            int row = i >> 5, c4 = i & 31;
            *(float4*)&wlds[row][c4 << 2] =
                *(const float4*)(w_ih + (size_t)(j0 + row) * H + c0 + (c4 << 2));
        }
        for (int i = tid; i < 16 * 32; i += 256) {
            int row = i >> 5, c4 = i & 31;
            float4 e = *(const float4*)(token_emb + (size_t)(v0 + row) * H + c0 + (c4 << 2));
            e.x = fmaxf(e.x, 0.f); e.y = fmaxf(e.y, 0.f);
            e.z = fmaxf(e.z, 0.f); e.w = fmaxf(e.w, 0.f);
            *(float4*)&elds[row][c4 << 2] = e;
        }
        __syncthreads();
        #pragma unroll 8
        for (int c = 0; c < 128; c += 4) {
            float4 wa = *(const float4*)&wlds[jl][c];
            float4 wb = *(const float4*)&wlds[32 + jl][c];
            float4 wc = *(const float4*)&wlds[64 + jl][c];
            float4 ea = *(const float4*)&elds[vl][c];
            float4 eb = *(const float4*)&elds[vl + 8][c];
            acc[0][0] += ea.x*wa.x + ea.y*wa.y + ea.z*wa.z + ea.w*wa.w;
            acc[0][1] += ea.x*wb.x + ea.y*wb.y + ea.z*wb.z + ea.w*wb.w;
            acc[0][2] += ea.x*wc.x + ea.y*wc.y + ea.z*wc.z + ea.w*wc.w;
            acc[1][0] += eb.x*wa.x + eb.y*wa.y + eb.z*wa.z + eb.w*wa.w;
            acc[1][1] += eb.x*wb.x + eb.y*wb.y + eb.z*wb.z + eb.w*wb.w;
            acc[1][2] += eb.x*wc.x + eb.y*wc.y + eb.z*wc.z + eb.w*wc.w;
        }
    }
    #pragma unroll
    for (int p = 0; p < 2; ++p) {
        int v = v0 + vl + (p << 3);
        #pragma unroll
        for (int s = 0; s < 3; ++s) {
            int j = j0 + (s << 5) + jl;
            gi_out[(size_t)v * H3 + j] = acc[p][s] + b_ih[j];
        }
    }
}

// ---------------- persistent GRU scan, clustered (256 WGs x 128 thr) ----------------
// BYTE-IDENTICAL to the R14-proven kernel. Unified write-once fragment-major
// hsp (258 slots: 0=h0, 1..256=steps, 257=EOS); step t reads slot t (sc1 u64,
// 512B-contiguous per instruction), writes slot t+1 via wave-local LDS staging
// -> 2 coalesced sc1 u64 stores per lane. RMW clusterbar per step.
__global__ __launch_bounds__(128, 1) void k_scan(
        const int* __restrict__ goal, const int* __restrict__ stem,
        const float* __restrict__ stem_emb,
        const s16* __restrict__ w_hi, const s16* __restrict__ w_lo,
        const float* __restrict__ b_hh, const float* __restrict__ gi_tok,
        unsigned* __restrict__ hsp, unsigned* bar) {
    __shared__ s16 wlds[96 * 512];       // 96 KB, viewed as [6][16][64][8]
    __shared__ unsigned stage[2][512];   // 2 KB per wave, fragment-major staging
    const int tid = threadIdx.x;
    const int wg = blockIdx.x;
    const int c = wg & 7;
    const int jt = wg >> 3;
    const int w = tid >> 6;
    const int l = tid & 63;
    const int ln = l & 15;
    const int kg = l >> 4;
    const int row0 = c * 32 + w * 16;   // this wave's 16 batch rows
    const int j = jt * 16 + ln;

    // one-time: stage weight slice into LDS, fragment-major.
    for (int i = tid; i < 6144; i += 128) {
        int lane = i & 63;
        int chunk = i >> 6;           // 0..95 = g2*16 + kcIdx
        int g2 = chunk >> 4;          // gate*2 + hl
        int kcIdx = chunk & 15;
        int gate = g2 >> 1, hl = g2 & 1;
        int lnn = lane & 15, kgg = lane >> 4;
        const s16* src = (hl ? w_lo : w_hi) +
                         ((size_t)(gate * H + jt * 16 + lnn)) * H + kcIdx * 32 + kgg * 8;
        *(s16x8*)(wlds + (size_t)i * 8) = *(const s16x8*)src;
    }
    // one-time: h0 (packed split) into hsp slot 0, fragment-major.
    // WG jt inits row b = c*32 + jt; thread tid covers cols tid*4 .. tid*4+4.
    {
        int b = c * 32 + jt;
        int blk = c * 2 + (jt >> 4);
        int lne = jt & 15;
        float4 v = ((const float4*)(stem_emb + (size_t)stem[b] * H))[tid];
        float xs[4] = {v.x, v.y, v.z, v.w};
        #pragma unroll
        for (int qq = 0; qq < 4; ++qq) {
            int col = tid * 4 + qq;
            int ku = col >> 1, s = col & 1;
            int ii = ku & 3, kgc = (ku >> 2) & 3, kc = ku >> 4;
            size_t slot = (size_t)blk * 8192 +
                          (size_t)(((kc * 4 + ii) * 64 + 16 * kgc + lne) * 2 + s);
            __hip_atomic_store(hsp + slot, packsplit(xs[qq]),
                               __ATOMIC_RELAXED, __HIP_MEMORY_SCOPE_AGENT);
        }
    }
    // hprev in registers: exact h0 at this lane's (b, j) positions
    float hprev[4];
    #pragma unroll
    for (int q = 0; q < 4; ++q) {
        int b = row0 + kg * 4 + q;
        hprev[q] = stem_emb[(size_t)stem[b] * H + j];
    }
    clusterbar(bar, c, 1u, tid);

    const float bhr = b_hh[j], bhz = b_hh[H + j], bhn = b_hh[2 * H + j];
    // epilogue constants
    const int ii2g = ((ln >> 1) & 3) * 2 + (ln >> 3);
    const int sbit = ln & 1;
    const size_t wavebase = (size_t)(c * 2 + w) * 4096 +
                            (size_t)(jt >> 1) * 256 + (size_t)(jt & 1) * 32 + (l & 31);

    for (int t = 0; t <= L; ++t) {
        const int tau_out = (t < L) ? t + 1 : 257;
        const u64* ap = (const u64*)hsp + (size_t)t * (SLOT / 2) +
                        (size_t)(c * 2 + w) * 4096 + l;

        // token + gi prefetch (normal cached loads)
        int bq[4];
        float g0[4], g1[4], g2v[4];
        #pragma unroll
        for (int q = 0; q < 4; ++q) {
            bq[q] = row0 + kg * 4 + q;
            int v = (t < L) ? goal[(size_t)bq[q] * L + t] : EOS_TOK;
            const float* gi = gi_tok + (size_t)v * H3;
            g0[q] = gi[j];
            g1[q] = gi[H + j];
            g2v[q] = gi[2 * H + j];
        }

        // A-loads: instruction kcii reads 64 lanes x 8B contiguous (512 B)
        u64 av[64];
        #pragma unroll
        for (int kcii = 0; kcii < 64; ++kcii)
            av[kcii] = __hip_atomic_load(ap + (size_t)kcii * 64,
                                         __ATOMIC_RELAXED, __HIP_MEMORY_SCOPE_AGENT);

        f32x4v ar{}, az{}, an{};
        #pragma unroll
        for (int kcIdx = 0; kcIdx < 16; ++kcIdx) {
            s16x8 Ah, Al;
            #pragma unroll
            for (int i = 0; i < 4; ++i) {
                u64 wv = av[kcIdx * 4 + i];
                unsigned lo32 = (unsigned)wv, hi32 = (unsigned)(wv >> 32);
                Ah[2 * i]     = (s16)(lo32 & 0xffff);
                Al[2 * i]     = (s16)(lo32 >> 16);
                Ah[2 * i + 1] = (s16)(hi32 & 0xffff);
                Al[2 * i + 1] = (s16)(hi32 >> 16);
            }
            const s16* bb = wlds + ((size_t)(kcIdx * 64 + l)) * 8;
            s16x8 Rh = *(const s16x8*)(bb);
            s16x8 Rl = *(const s16x8*)(bb + 8192);
            s16x8 Zh = *(const s16x8*)(bb + 16384);
            s16x8 Zl = *(const s16x8*)(bb + 24576);
            s16x8 Nh = *(const s16x8*)(bb + 32768);
            s16x8 Nl = *(const s16x8*)(bb + 40960);
            ar = __builtin_amdgcn_mfma_f32_16x16x32_bf16(Ah, Rh, ar, 0, 0, 0);
            az = __builtin_amdgcn_mfma_f32_16x16x32_bf16(Ah, Zh, az, 0, 0, 0);
            an = __builtin_amdgcn_mfma_f32_16x16x32_bf16(Ah, Nh, an, 0, 0, 0);
            ar = __builtin_amdgcn_mfma_f32_16x16x32_bf16(Ah, Rl, ar, 0, 0, 0);
            az = __builtin_amdgcn_mfma_f32_16x16x32_bf16(Ah, Zl, az, 0, 0, 0);
            an = __builtin_amdgcn_mfma_f32_16x16x32_bf16(Ah, Nl, an, 0, 0, 0);
            ar = __builtin_amdgcn_mfma_f32_16x16x32_bf16(Al, Rh, ar, 0, 0, 0);
            az = __builtin_amdgcn_mfma_f32_16x16x32_bf16(Al, Zh, az, 0, 0, 0);
            an = __builtin_amdgcn_mfma_f32_16x16x32_bf16(Al, Nh, an, 0, 0, 0);
        }

        // epilogue: compute, pack, stage in LDS (wave-local), store coalesced
        unsigned pv[4];
        #pragma unroll
        for (int q = 0; q < 4; ++q) {
            float r = sigmoidf_(g0[q] + ar[q] + bhr);
            float z = sigmoidf_(g1[q] + az[q] + bhz);
            float x = g2v[q] + r * (an[q] + bhn);
            float e = __expf(-2.f * x);
            float nn = (1.f - e) / (1.f + e);         // tanh(x)
            float hn = (1.f - z) * nn + z * hprev[q];
            hprev[q] = hn;
            pv[q] = packsplit(hn);
        }
        {
            unsigned* st = stage[w];
            #pragma unroll
            for (int q = 0; q < 4; ++q)
                st[ii2g * 32 + (kg * 4 + q) * 2 + sbit] = pv[q];
            const u64* stu = (const u64*)stage[w];
            u64* outp = (u64*)hsp + (size_t)tau_out * (SLOT / 2) + wavebase;
            #pragma unroll
            for (int k = 0; k < 2; ++k) {
                int iis = k * 2 + (l >> 5);
                __hip_atomic_store(outp + (size_t)iis * 64, stu[iis * 32 + (l & 31)],
                                   __ATOMIC_RELAXED, __HIP_MEMORY_SCOPE_AGENT);
            }
        }

        if (t < L) clusterbar(bar, c, (unsigned)(t + 2), tid);
    }
}

// ---------------- fused MLP via MFMA — ONE launch over all 257 outputs ----------------
// block bi: slotIdx = 1 + (bi>>2) in 1..257; col = slotIdx==257 ? 0 : slotIdx;
// rows b0 = (bi&3)*64 .. +64 of that slot. Fragment-major packed states,
// relu on unpack; packed v1 in LDS. Index math proven equivalent to the
// R14-passing two-launch version.
__global__ __launch_bounds__(256, 1) void k_mlp_mfma(
        const unsigned* __restrict__ hsp,
        const s16* __restrict__ w0h, const s16* __restrict__ w0l,
        const float* __restrict__ b0v,
        const s16* __restrict__ w1h, const s16* __restrict__ w1l,
        const float* __restrict__ b1v,
        const float* __restrict__ w2v, const float* __restrict__ b2v,
        float* __restrict__ out) {
    __shared__ unsigned v1s[64 * 512];   // 128 KB, packed-split v1
    __shared__ float red[4][64];
    const int tid = threadIdx.x;
    const int wid = tid >> 6;
    const int l = tid & 63;
    const int ln = l & 15;
    const int kg = l >> 4;
    const int bi = blockIdx.x;
    const int slotIdx = 1 + (bi >> 2);
    const int col = (slotIdx == 257) ? 0 : slotIdx;
    const int b0 = (bi & 3) * 64;
    const u64* slotb = (const u64*)hsp + (size_t)slotIdx * (SLOT / 2);
    const int blk0 = b0 >> 4;

    f32x4v acc[4][8];
    #pragma unroll
    for (int mf = 0; mf < 4; ++mf)
        #pragma unroll
        for (int nf = 0; nf < 8; ++nf) acc[mf][nf] = f32x4v{};

    // ---- GEMM1: v1 = relu(relu(h) @ w0.T + b0), fragment-major packed h ----
    for (int kc = 0; kc < H; kc += 32) {
        const int kcIdx = kc >> 5;
        s16x8 Ah[4], Al[4];
        #pragma unroll
        for (int mf = 0; mf < 4; ++mf) {
            const u64* sb = slotb + (size_t)(blk0 + mf) * 4096 + l;
            #pragma unroll
            for (int i = 0; i < 4; ++i) {
                u64 wv = sb[(size_t)(kcIdx * 4 + i) * 64];
                unsigned lo32 = relu_pk((unsigned)wv);
                unsigned hi32 = relu_pk((unsigned)(wv >> 32));
                Ah[mf][2 * i]     = (s16)(lo32 & 0xffff);
                Al[mf][2 * i]     = (s16)(lo32 >> 16);
                Ah[mf][2 * i + 1] = (s16)(hi32 & 0xffff);
                Al[mf][2 * i + 1] = (s16)(hi32 >> 16);
            }
        }
        #pragma unroll
        for (int nf = 0; nf < 8; ++nf) {
            const int n = wid * 128 + nf * 16 + ln;
            s16x8 Bh = *(const s16x8*)(w0h + (size_t)n * H + kc + kg * 8);
            s16x8 Bl = *(const s16x8*)(w0l + (size_t)n * H + kc + kg * 8);
            #pragma unroll
            for (int mf = 0; mf < 4; ++mf) {
                acc[mf][nf] = __builtin_amdgcn_mfma_f32_16x16x32_bf16(Ah[mf], Bh, acc[mf][nf], 0, 0, 0);
                acc[mf][nf] = __builtin_amdgcn_mfma_f32_16x16x32_bf16(Ah[mf], Bl, acc[mf][nf], 0, 0, 0);
                acc[mf][nf] = __builtin_amdgcn_mfma_f32_16x16x32_bf16(Al[mf], Bh, acc[mf][nf], 0, 0, 0);
            }
        }
    }
    float bn[8];
    #pragma unroll
    for (int nf = 0; nf < 8; ++nf) bn[nf] = b0v[wid * 128 + nf * 16 + ln];
    #pragma unroll
    for (int mf = 0; mf < 4; ++mf)
        #pragma unroll
        for (int nf = 0; nf < 8; ++nf)
            #pragma unroll
            for (int q = 0; q < 4; ++q) {
                int m = mf * 16 + kg * 4 + q;
                int n = wid * 128 + nf * 16 + ln;
                v1s[m * 512 + (n ^ ((m & 7) << 2))] = packsplit(fmaxf(acc[mf][nf][q] + bn[nf], 0.f));
            }
    __syncthreads();

    // ---- GEMM2: v2 = relu(v1 @ w1.T + b1); lik = v2 . w2 ----
    #pragma unroll
    for (int mf = 0; mf < 4; ++mf)
        #pragma unroll
        for (int nf = 0; nf < 8; ++nf) acc[mf][nf] = f32x4v{};
    for (int kc = 0; kc < H; kc += 32) {
        s16x8 Ah[4], Al[4];
        #pragma unroll
        for (int mf = 0; mf < 4; ++mf) {
            const int rr = mf * 16 + ln;
            const int cx = (rr & 7) << 2;
            const int k0 = kc + kg * 8;
            uint4 p0 = *(const uint4*)(v1s + rr * 512 + (k0 ^ cx));
            uint4 p1 = *(const uint4*)(v1s + rr * 512 + ((k0 + 4) ^ cx));
            unsigned pv[8] = {p0.x, p0.y, p0.z, p0.w, p1.x, p1.y, p1.z, p1.w};
            #pragma unroll
            for (int i = 0; i < 8; ++i) {
                Ah[mf][i] = (s16)(pv[i] & 0xffff);
                Al[mf][i] = (s16)(pv[i] >> 16);
            }
        }
        #pragma unroll
        for (int nf = 0; nf < 8; ++nf) {
            const int n = wid * 128 + nf * 16 + ln;
            s16x8 Bh = *(const s16x8*)(w1h + (size_t)n * H + kc + kg * 8);
            s16x8 Bl = *(const s16x8*)(w1l + (size_t)n * H + kc + kg * 8);
            #pragma unroll
            for (int mf = 0; mf < 4; ++mf) {
                acc[mf][nf] = __builtin_amdgcn_mfma_f32_16x16x32_bf16(Ah[mf], Bh, acc[mf][nf], 0, 0, 0);
                acc[mf][nf] = __builtin_amdgcn_mfma_f32_16x16x32_bf16(Ah[mf], Bl, acc[mf][nf], 0, 0, 0);
                acc[mf][nf] = __builtin_amdgcn_mfma_f32_16x16x32_bf16(Al[mf], Bh, acc[mf][nf], 0, 0, 0);
            }
        }
    }
    float b1n[8], w2n[8];
    #pragma unroll
    for (int nf = 0; nf < 8; ++nf) {
        int n = wid * 128 + nf * 16 + ln;
        b1n[nf] = b1v[n];
        w2n[nf] = w2v[n];
    }
    float psum[4][4];
    #pragma unroll
    for (int mf = 0; mf < 4; ++mf)
        #pragma unroll
        for (int q = 0; q < 4; ++q) {
            float s = 0.f;
            #pragma unroll
            for (int nf = 0; nf < 8; ++nf)
                s += fmaxf(acc[mf][nf][q] + b1n[nf], 0.f) * w2n[nf];
            psum[mf][q] = s;
        }
    #pragma unroll
    for (int mf = 0; mf < 4; ++mf)
        #pragma unroll
        for (int q = 0; q < 4; ++q) {
            float s = psum[mf][q];
            #pragma unroll
            for (int msk = 1; msk < 16; msk <<= 1)
                s += __shfl_xor(s, msk, 64);
            psum[mf][q] = s;
        }
    if (ln == 0) {
        #pragma unroll
        for (int mf = 0; mf < 4; ++mf)
            #pragma unroll
            for (int q = 0; q < 4; ++q)
                red[wid][mf * 16 + kg * 4 + q] = psum[mf][q];
    }
    __syncthreads();
    if (tid < 64) {
        float s = b2v[0] + red[0][tid] + red[1][tid] + red[2][tid] + red[3][tid];
        out[(size_t)(b0 + tid) * OUTC + col] = s;
    }
}

extern "C" void kernel_launch(void* const* d_in, const int* in_sizes, int n_in,
                              void* d_out, int out_size, void* d_ws, size_t ws_size,
                              hipStream_t stream) {
    (void)in_sizes; (void)n_in; (void)out_size; (void)ws_size;
    const int* stem = (const int*)d_in[0];
    const int* goal = (const int*)d_in[1];
    const float* stem_emb = (const float*)d_in[2];
    const float* token_emb = (const float*)d_in[3];
    const float* w_ih = (const float*)d_in[4];
    const float* w_hh = (const float*)d_in[5];
    const float* b_ih = (const float*)d_in[6];
    const float* b_hh = (const float*)d_in[7];
    const float* w0 = (const float*)d_in[8];
    const float* b0 = (const float*)d_in[9];
    const float* w1 = (const float*)d_in[10];
    const float* b1 = (const float*)d_in[11];
    const float* w2 = (const float*)d_in[12];
    const float* b2 = (const float*)d_in[13];
    float* out = (float*)d_out;

    char* p = (char*)d_ws;
    float* gi_tok = (float*)p;      p += (size_t)TOKV * H3 * 4;
    s16* whh_h = (s16*)p;           p += (size_t)H3 * H * 2;
    s16* whh_l = (s16*)p;           p += (size_t)H3 * H * 2;
    s16* w0h = (s16*)p;             p += (size_t)H * H * 2;
    s16* w0l = (s16*)p;             p += (size_t)H * H * 2;
    s16* w1h = (s16*)p;             p += (size_t)H * H * 2;
    s16* w1l = (s16*)p;             p += (size_t)H * H * 2;
    unsigned* bar = (unsigned*)p;   p += 4096;
    unsigned* hsp = (unsigned*)p;   // 258 packed slots: 0=h0, 1..256=steps, 257=EOS

    hipMemsetAsync(bar, 0, 4096, stream);

    // prep (2 launches)
    k_split_all<<<1280, 256, 0, stream>>>(w_hh, whh_h, whh_l,
                                          w0, w0h, w0l, w1, w1h, w1l);
    k_gi_tok<<<128, 256, 0, stream>>>(token_emb, w_ih, b_ih, gi_tok);

    // persistent clustered scan (h0 init + 256 GRU steps + EOS step).
    // Cooperative launch preferred; on ANY failure fall back to a plain
    // launch (1 WG/CU resources + idle GPU => co-resident in practice).
    {
        const int* goal_a = goal;
        const int* stem_a = stem;
        const float* stem_emb_a = stem_emb;
        const s16* whh_h_a = whh_h;
        const s16* whh_l_a = whh_l;
        const float* b_hh_a = b_hh;
        const float* gi_tok_a = gi_tok;
        unsigned* hsp_a = hsp;
        unsigned* bar_a = bar;
        void* kargs[] = {(void*)&goal_a, (void*)&stem_a, (void*)&stem_emb_a,
                         (void*)&whh_h_a, (void*)&whh_l_a, (void*)&b_hh_a,
                         (void*)&gi_tok_a, (void*)&hsp_a, (void*)&bar_a};
        hipError_t ce = hipLaunchCooperativeKernel((void*)k_scan, dim3(256),
                                                   dim3(128), kargs, 0, stream);
        if (ce != hipSuccess) {
            k_scan<<<256, 128, 0, stream>>>(goal, stem, stem_emb, whh_h, whh_l,
                                            b_hh, gi_tok, hsp, bar);
        }
    }

    // MLP: one launch, all 257 output columns
    k_mlp_mfma<<<1028, 256, 0, stream>>>(hsp, w0h, w0l, b0,
                                         w1h, w1l, b1, w2, b2, out);
}